// Round 2
// baseline (941.155 us; speedup 1.0000x reference)
//
#include <hip/hip_runtime.h>
#include <hip/hip_bf16.h>

typedef unsigned short ushort_t;
typedef __attribute__((ext_vector_type(4))) float floatx4;
typedef __attribute__((ext_vector_type(8))) __bf16 bf16x8;
typedef __attribute__((ext_vector_type(4))) unsigned short ushortx4;

// ---------- bf16 helpers ----------
static __device__ __forceinline__ float b2f(ushort_t u) {
  union { unsigned int i; float f; } v; v.i = ((unsigned int)u) << 16; return v.f;
}
static __device__ __forceinline__ ushort_t f2b(float f) {
  unsigned int x = __float_as_uint(f);
  unsigned int r = (x + 0x7fffu + ((x >> 16) & 1u)) >> 16;
  return (ushort_t)r;
}

// =========================================================================
// GEMM: C[M,N] = A[M,K] @ B[N,K]^T (+bias[col]).  fp32 in, fp32 out.
// Internally: split each operand to bf16 hi+lo, 3 MFMA passes (hi*hi +
// hi*lo + lo*hi) -> ~2^-17 relative error, fp32-grade for this test.
// MODE 0: store fp32 row-major (ldc=N, + z*cBatch); bias optional
// MODE 2: store fp32 TRANSPOSED batched: out[(b*N+col)*1024 + (m&1023)]
// Block 256 thr = 4 waves; tile 128x128; wave = 64x64 via 4x4 mfma 16x16x32.
// =========================================================================
template<int MODE>
__global__ __launch_bounds__(256, 2) void gemm_bt(
    const float* __restrict__ A, const float* __restrict__ Bm,
    const float* __restrict__ bias, float* __restrict__ Cout,
    int M, int N, int K, long aBatch, long bBatch, long cBatch)
{
  __shared__ __align__(16) ushort_t AsH[128 * 40];
  __shared__ __align__(16) ushort_t AsL[128 * 40];
  __shared__ __align__(16) ushort_t BsH[128 * 40];
  __shared__ __align__(16) ushort_t BsL[128 * 40];

  const int tid  = threadIdx.x;
  const int wid  = tid >> 6;
  const int lane = tid & 63;
  const int quad = lane >> 4;
  const int l16  = lane & 15;
  const int m0 = blockIdx.y * 128;
  const int n0 = blockIdx.x * 128;
  const int z  = blockIdx.z;

  A  += (long)z * aBatch;
  Bm += (long)z * bBatch;

  const int wr = (wid >> 1) * 64;   // wave row offset in tile
  const int wc = (wid & 1) * 64;    // wave col offset in tile

  floatx4 acc[4][4];
#pragma unroll
  for (int i = 0; i < 4; ++i)
#pragma unroll
    for (int j = 0; j < 4; ++j)
      acc[i][j] = (floatx4){0.f, 0.f, 0.f, 0.f};

  for (int k0 = 0; k0 < K; k0 += 32) {
    __syncthreads();
    // stage A,B tiles: 128 rows x 32 fp32 each; float4 chunks; 8 chunks/row.
#pragma unroll
    for (int pass = 0; pass < 4; ++pass) {
      int c   = tid + pass * 256;         // 0..1023
      int row = c >> 3;
      int kc  = (c & 7) * 4;
      floatx4 va = *(const floatx4*)(A + (long)(m0 + row) * K + k0 + kc);
      floatx4 vb = *(const floatx4*)(Bm + (long)(n0 + row) * K + k0 + kc);
      ushortx4 ah, al, bh, bl;
#pragma unroll
      for (int r = 0; r < 4; ++r) {
        ah[r] = f2b(va[r]); al[r] = f2b(va[r] - b2f(ah[r]));
        bh[r] = f2b(vb[r]); bl[r] = f2b(vb[r] - b2f(bh[r]));
      }
      *(ushortx4*)(&AsH[row * 40 + kc]) = ah;
      *(ushortx4*)(&AsL[row * 40 + kc]) = al;
      *(ushortx4*)(&BsH[row * 40 + kc]) = bh;
      *(ushortx4*)(&BsL[row * 40 + kc]) = bl;
    }
    __syncthreads();

    bf16x8 afH[4], afL[4], bfH[4], bfL[4];
#pragma unroll
    for (int i = 0; i < 4; ++i) {
      afH[i] = *(const bf16x8*)(&AsH[(wr + i * 16 + l16) * 40 + quad * 8]);
      afL[i] = *(const bf16x8*)(&AsL[(wr + i * 16 + l16) * 40 + quad * 8]);
    }
#pragma unroll
    for (int j = 0; j < 4; ++j) {
      bfH[j] = *(const bf16x8*)(&BsH[(wc + j * 16 + l16) * 40 + quad * 8]);
      bfL[j] = *(const bf16x8*)(&BsL[(wc + j * 16 + l16) * 40 + quad * 8]);
    }
#pragma unroll
    for (int i = 0; i < 4; ++i)
#pragma unroll
      for (int j = 0; j < 4; ++j) {
        acc[i][j] = __builtin_amdgcn_mfma_f32_16x16x32_bf16(afL[i], bfH[j], acc[i][j], 0, 0, 0);
        acc[i][j] = __builtin_amdgcn_mfma_f32_16x16x32_bf16(afH[i], bfL[j], acc[i][j], 0, 0, 0);
        acc[i][j] = __builtin_amdgcn_mfma_f32_16x16x32_bf16(afH[i], bfH[j], acc[i][j], 0, 0, 0);
      }
  }

  // epilogue: lane holds col = l16; rows quad*4+r within each 16x16 sub-tile
#pragma unroll
  for (int j = 0; j < 4; ++j) {
    int col = n0 + wc + j * 16 + l16;
    float bv = (bias != nullptr) ? bias[col] : 0.f;
#pragma unroll
    for (int i = 0; i < 4; ++i) {
      int mbase = m0 + wr + i * 16 + quad * 4;
      if constexpr (MODE == 2) {
        int b    = mbase >> 10;
        int jrow = mbase & 1023;           // rows r=0..3 consecutive
        floatx4 pk;
#pragma unroll
        for (int r = 0; r < 4; ++r) pk[r] = acc[i][j][r] + bv;
        *(floatx4*)(Cout + ((long)b * N + col) * 1024 + jrow) = pk;
      } else {
#pragma unroll
        for (int r = 0; r < 4; ++r) {
          long idx = (long)z * cBatch + (long)(mbase + r) * N + col;
          Cout[idx] = acc[i][j][r] + bv;
        }
      }
    }
  }
}

// =========================================================================
// Attention over the batch axis: per (n,h), q,k,v are (8 x 64).
// One wave per (n,h); 4 pairs per 256-thread block.
// =========================================================================
__global__ __launch_bounds__(256) void attn_kernel(
    const float* __restrict__ qkv, float* __restrict__ outp)
{
  __shared__ float qs[4][8][65], ks[4][8][65], vs[4][8][65];
  __shared__ float aw[4][64];
  const int w    = threadIdx.x >> 6;
  const int lane = threadIdx.x & 63;
  const int p = blockIdx.x * 4 + w;
  const int n = p >> 3, h = p & 7;

  const float* base = qkv + (long)n * 1536 + h * 64;
#pragma unroll
  for (int i = 0; i < 8; ++i) {
    long off = (long)i * 1024 * 1536;
    qs[w][i][lane] = base[off + lane];
    ks[w][i][lane] = base[off + 512 + lane];
    vs[w][i][lane] = base[off + 1024 + lane];
  }
  __syncthreads();

  const int i = lane >> 3, j = lane & 7;   // lane = (i,j) score pair
  float s = 0.f;
#pragma unroll 8
  for (int d = 0; d < 64; ++d) s += qs[w][i][d] * ks[w][j][d];
  s *= 0.125f;   // 1/sqrt(64)

  float m = s;
  m = fmaxf(m, __shfl_xor(m, 1));
  m = fmaxf(m, __shfl_xor(m, 2));
  m = fmaxf(m, __shfl_xor(m, 4));
  float e = __expf(s - m);
  float sum = e;
  sum += __shfl_xor(sum, 1);
  sum += __shfl_xor(sum, 2);
  sum += __shfl_xor(sum, 4);
  aw[w][lane] = e / sum;
  __syncthreads();

  // lane = d; o[i][d] = sum_j a[i][j] * v[j][d]
  float* ob = outp + (long)n * 512 + h * 64 + lane;
#pragma unroll
  for (int ii = 0; ii < 8; ++ii) {
    float acc = 0.f;
#pragma unroll
    for (int jj = 0; jj < 8; ++jj) acc += aw[w][ii * 8 + jj] * vs[w][jj][lane];
    ob[(long)ii * 1024 * 512] = acc;
  }
}

// =========================================================================
// x_out = LayerNorm(x_prev + agg), row length 512. Wave per row.
// =========================================================================
__global__ __launch_bounds__(256) void ln_kernel(
    const float* __restrict__ xprev, const float* __restrict__ agg,
    float* __restrict__ xout)
{
  const int w = threadIdx.x >> 6, lane = threadIdx.x & 63;
  const long row = (long)blockIdx.x * 4 + w;
  const long base = row * 512;
  float v[8];
  float s = 0.f;
#pragma unroll
  for (int k = 0; k < 8; ++k) {
    v[k] = xprev[base + lane + 64 * k] + agg[base + lane + 64 * k];
    s += v[k];
  }
#pragma unroll
  for (int msk = 1; msk <= 32; msk <<= 1) s += __shfl_xor(s, msk);
  float mean = s * (1.f / 512.f);
  float vv = 0.f;
#pragma unroll
  for (int k = 0; k < 8; ++k) { float d = v[k] - mean; vv += d * d; }
#pragma unroll
  for (int msk = 1; msk <= 32; msk <<= 1) vv += __shfl_xor(vv, msk);
  float inv = rsqrtf(vv * (1.f / 512.f) + 1e-5f);
#pragma unroll
  for (int k = 0; k < 8; ++k)
    xout[base + lane + 64 * k] = (v[k] - mean) * inv;
}

// =========================================================================
// Heads: per row of x (8192x512) compute 8 dot products:
// mastery(1), diff(5), h1 = x@Wpre[:512], h2 = x@Wpre[512:]. Wave per row.
// =========================================================================
__global__ __launch_bounds__(256) void heads_kernel(
    const float* __restrict__ x,
    const float* __restrict__ Wcls, const float* __restrict__ bcls,
    const float* __restrict__ Wdiff, const float* __restrict__ bdiff,
    const float* __restrict__ Wpre,
    float* __restrict__ mastery, float* __restrict__ diff,
    float* __restrict__ h1, float* __restrict__ h2)
{
  const int w = threadIdx.x >> 6, lane = threadIdx.x & 63;
  const long row = (long)blockIdx.x * 4 + w;
  float xv[8];
#pragma unroll
  for (int k = 0; k < 8; ++k) xv[k] = x[row * 512 + lane + 64 * k];

#pragma unroll
  for (int o = 0; o < 8; ++o) {
    const float* wp = (o == 0) ? Wcls
                    : (o <= 5) ? (Wdiff + (o - 1) * 512)
                    : (o == 6) ? Wpre : (Wpre + 512);
    float p = 0.f;
#pragma unroll
    for (int k = 0; k < 8; ++k) p += xv[k] * wp[lane + 64 * k];
#pragma unroll
    for (int msk = 1; msk <= 32; msk <<= 1) p += __shfl_xor(p, msk);
    if (lane == 0) {
      if (o == 0)      mastery[row] = p + bcls[0];
      else if (o <= 5) diff[row * 5 + (o - 1)] = p + bdiff[o - 1];
      else if (o == 6) h1[row] = p;
      else             h2[row] = p;
    }
  }
}

// =========================================================================
// prereq[b, i*1023 + pos(j)] = h1[b,i] + h2[b,j] + b_pre,  j != i
// =========================================================================
__global__ __launch_bounds__(256) void prereq_kernel(
    const float* __restrict__ h1, const float* __restrict__ h2,
    const float* __restrict__ bpre, float* __restrict__ outp)
{
  const int b = blockIdx.y, i = blockIdx.x;
  const float base = h1[b * 1024 + i] + bpre[0];
  const long ob = (long)b * (1024 * 1023) + (long)i * 1023;
#pragma unroll
  for (int r = 0; r < 4; ++r) {
    int j = r * 256 + threadIdx.x;
    if (j == i) continue;
    int pos = (j < i) ? j : j - 1;
    outp[ob + pos] = base + h2[b * 1024 + j];
  }
}

// =========================================================================
// xm[b,c] = mean over n of x[b,n,c]
// =========================================================================
__global__ __launch_bounds__(256) void pool_mean_kernel(
    const float* __restrict__ x, float* __restrict__ xm)
{
  const int b = blockIdx.x >> 1;
  const int c = (blockIdx.x & 1) * 256 + threadIdx.x;
  float s = 0.f;
  for (int n = 0; n < 1024; ++n) s += x[((long)b * 1024 + n) * 512 + c];
  xm[b * 512 + c] = s * (1.f / 1024.f);
}

// graph[b,o] = xm[b] . Wpool[o] + b_pool[o]
__global__ __launch_bounds__(256) void graph_kernel(
    const float* __restrict__ xm, const float* __restrict__ Wpool,
    const float* __restrict__ bpool, float* __restrict__ g)
{
  const int gi = blockIdx.x * 256 + threadIdx.x;
  const int b = gi >> 9, o = gi & 511;
  float s = bpool[o];
  for (int hh = 0; hh < 512; ++hh) s += xm[b * 512 + hh] * Wpool[o * 512 + hh];
  g[gi] = s;
}

// =========================================================================
extern "C" void kernel_launch(void* const* d_in, const int* in_sizes, int n_in,
                              void* d_out, int out_size, void* d_ws, size_t ws_size,
                              hipStream_t stream)
{
  const float* CF    = (const float*)d_in[0];
  const float* ADJ   = (const float*)d_in[1];
  // d_in[2] edge_types (int), d_in[3] concept_mask (bool): unused
  const float* Wemb  = (const float*)d_in[4];
  const float* bemb  = (const float*)d_in[5];
  const float* Win   = (const float*)d_in[6];
  const float* bin   = (const float*)d_in[7];
  const float* Wout  = (const float*)d_in[8];
  const float* bout  = (const float*)d_in[9];
  const float* Wconv = (const float*)d_in[10];
  const float* bconv = (const float*)d_in[11];
  const float* Wcls  = (const float*)d_in[12];
  const float* bcls  = (const float*)d_in[13];
  const float* Wdiff = (const float*)d_in[14];
  const float* bdiff = (const float*)d_in[15];
  const float* Wpre  = (const float*)d_in[16];
  const float* bpre  = (const float*)d_in[17];
  const float* Wpool = (const float*)d_in[18];
  const float* bpool = (const float*)d_in[19];

  // workspace layout (floats). qkv region (48 MB) is reused after attention:
  //   att   aliases qkv[0        : 4194304)
  //   convT aliases qkv[4194304  : 8388608)
  //   agg   aliases qkv[8388608  : 12582912)
  float* xbuf    = (float*)d_ws;            // 8192*512
  float* qkv     = xbuf + 4194304;          // 8192*1536
  float* attnout = qkv + 12582912;          // 8192*512
  float* att     = qkv;
  float* convT   = qkv + 4194304;           // (8,512,1024)
  float* agg     = qkv + 8388608;           // 8192*512
  float* h1      = attnout + 4194304;       // 8192
  float* h2      = h1 + 8192;               // 8192
  float* xm      = h2 + 8192;               // 4096

  // output layout (flat concat, fp32)
  float* out_x       = (float*)d_out;       // 8*1024*512
  float* out_mastery = out_x + 4194304;     // 8192
  float* out_diff    = out_mastery + 8192;  // 40960
  float* out_prereq  = out_diff + 40960;    // 8*1024*1023
  float* out_graph   = out_prereq + 8380416;// 4096

  dim3 blk(256);

  // x0 = CF @ Wemb^T + bemb   (8192 x 512 x 256)
  gemm_bt<0><<<dim3(4, 64, 1), blk, 0, stream>>>(CF, Wemb, bemb, xbuf,
                                                 8192, 512, 256, 0, 0, 0);
  for (int l = 0; l < 3; ++l) {
    // qkv = x @ Win[l]^T + bin[l]   (8192 x 1536 x 512)
    gemm_bt<0><<<dim3(12, 64, 1), blk, 0, stream>>>(
        xbuf, Win + (long)l * 1536 * 512, bin + l * 1536, qkv,
        8192, 1536, 512, 0, 0, 0);
    // attention over batch axis
    attn_kernel<<<dim3(2048), blk, 0, stream>>>(qkv, attnout);
    // att = o @ Wout[l]^T + bout[l]   (qkv region is dead -> att aliases it)
    gemm_bt<0><<<dim3(4, 64, 1), blk, 0, stream>>>(
        attnout, Wout + (long)l * 512 * 512, bout + l * 512, att,
        8192, 512, 512, 0, 0, 0);
    // convT = (att @ Wconv[l]^T + bconv[l]) stored transposed per-batch
    gemm_bt<2><<<dim3(4, 64, 1), blk, 0, stream>>>(
        att, Wconv + (long)l * 512 * 512, bconv + l * 512, convT,
        8192, 512, 512, 0, 0, 0);
    // agg[b] = adj[b] @ conv[b]  (batched 1024 x 512 x 1024; convT k-contig)
    gemm_bt<0><<<dim3(4, 8, 8), blk, 0, stream>>>(
        ADJ, convT, nullptr, agg,
        1024, 512, 1024, 1048576, 524288, 524288);
    // x = LN(x + agg)
    float* xo = (l == 2) ? out_x : xbuf;
    ln_kernel<<<dim3(2048), blk, 0, stream>>>(xbuf, agg, xo);
  }

  heads_kernel<<<dim3(2048), blk, 0, stream>>>(out_x, Wcls, bcls, Wdiff, bdiff,
                                               Wpre, out_mastery, out_diff, h1, h2);
  prereq_kernel<<<dim3(1024, 8), blk, 0, stream>>>(h1, h2, bpre, out_prereq);
  pool_mean_kernel<<<dim3(16), blk, 0, stream>>>(out_x, xm);
  graph_kernel<<<dim3(16), blk, 0, stream>>>(xm, Wpool, bpool, out_graph);
}

// Round 3
// 798.882 us; speedup vs baseline: 1.1781x; 1.1781x over previous
//
#include <hip/hip_runtime.h>
#include <hip/hip_bf16.h>

typedef unsigned short ushort_t;
typedef __attribute__((ext_vector_type(4))) float floatx4;
typedef __attribute__((ext_vector_type(8))) __bf16 bf16x8;
typedef __attribute__((ext_vector_type(4))) unsigned short ushortx4;

// ---------- bf16 helpers ----------
static __device__ __forceinline__ float b2f(ushort_t u) {
  union { unsigned int i; float f; } v; v.i = ((unsigned int)u) << 16; return v.f;
}
static __device__ __forceinline__ ushort_t f2b(float f) {
  unsigned int x = __float_as_uint(f);
  unsigned int r = (x + 0x7fffu + ((x >> 16) & 1u)) >> 16;
  return (ushort_t)r;
}
// async global->LDS, 16B per lane (dest = wave-uniform base + lane*16)
static __device__ __forceinline__ void glds16(const ushort_t* g, ushort_t* l) {
  __builtin_amdgcn_global_load_lds(
      (const __attribute__((address_space(1))) unsigned int*)g,
      (__attribute__((address_space(3))) unsigned int*)l, 16, 0, 0);
}

// =========================================================================
// GEMM: C[M,N] = A[M,K] @ B[N,K]^T (+bias[col]).  bf16 hi/lo 3-pass MFMA
// (hh + hl + lh) ~ 2^-17 relative error.
// B always pre-split (Bh,Bl ushort, k-contig), staged via global_load_lds.
// ASPLIT=true : A pre-split too (Ap=Ah, Al) -> global_load_lds.
// ASPLIT=false: Ap is fp32; split in-kernel (VGPR->ds_write).
// MODE 0: CoutF fp32 row-major (+z*cBatch)
// MODE 1: CoutH/CoutL bf16 pair row-major
// MODE 2: CoutH/CoutL pair TRANSPOSED batched: [(b*N+col)*1024 + (m&1023)]
// Block 256 = 4 waves; tile 128x128; wave 64x64 via 4x4 mfma 16x16x32.
// =========================================================================
template<int MODE, bool ASPLIT>
__global__ __launch_bounds__(256, 2) void gemm_bt(
    const void* __restrict__ Ap, const ushort_t* __restrict__ Alo,
    const ushort_t* __restrict__ Bh, const ushort_t* __restrict__ Bl,
    const float* __restrict__ bias,
    float* __restrict__ CoutF, ushort_t* __restrict__ CoutH, ushort_t* __restrict__ CoutL,
    int M, int N, int K, long aBatch, long bBatch, long cBatch)
{
  __shared__ __align__(16) ushort_t AsH[128 * 32];
  __shared__ __align__(16) ushort_t AsL[128 * 32];
  __shared__ __align__(16) ushort_t BsH[128 * 32];
  __shared__ __align__(16) ushort_t BsL[128 * 32];

  const int tid  = threadIdx.x;
  const int wid  = tid >> 6;
  const int lane = tid & 63;
  const int quad = lane >> 4;
  const int l16  = lane & 15;
  const int m0 = blockIdx.y * 128;
  const int n0 = blockIdx.x * 128;
  const int z  = blockIdx.z;

  const ushort_t* Ah = (const ushort_t*)Ap + (long)z * aBatch;
  const ushort_t* Al = Alo ? (Alo + (long)z * aBatch) : nullptr;
  const float*    Af = (const float*)Ap + (long)z * aBatch;
  Bh += (long)z * bBatch;
  Bl += (long)z * bBatch;

  const int wr = (wid >> 1) * 64;
  const int wc = (wid & 1) * 64;

  // staging address precompute (chunk = 16B = 8 ushorts; 512 chunks/plane)
  const int srow = tid >> 2, ssub = (tid & 3) * 8;
  const long ao0 = (long)(m0 + srow) * K + ssub, ao1 = ao0 + 64 * (long)K;
  const long bo0 = (long)(n0 + srow) * K + ssub, bo1 = bo0 + 64 * (long)K;
  const int frow = tid >> 3, fsub = (tid & 7) * 4;   // fp32 A path

  floatx4 acc[4][4];
#pragma unroll
  for (int i = 0; i < 4; ++i)
#pragma unroll
    for (int j = 0; j < 4; ++j) acc[i][j] = (floatx4){0.f, 0.f, 0.f, 0.f};

  for (int k0 = 0; k0 < K; k0 += 32) {
    __syncthreads();
    if constexpr (ASPLIT) {
      glds16(Ah + ao0 + k0, &AsH[tid * 8]);
      glds16(Ah + ao1 + k0, &AsH[tid * 8 + 2048]);
      glds16(Al + ao0 + k0, &AsL[tid * 8]);
      glds16(Al + ao1 + k0, &AsL[tid * 8 + 2048]);
    } else {
#pragma unroll
      for (int p = 0; p < 4; ++p) {
        int row = frow + p * 32;
        floatx4 va = *(const floatx4*)(Af + (long)(m0 + row) * K + k0 + fsub);
        ushortx4 ah, al;
#pragma unroll
        for (int r = 0; r < 4; ++r) {
          ah[r] = f2b(va[r]); al[r] = f2b(va[r] - b2f(ah[r]));
        }
        *(ushortx4*)(&AsH[row * 32 + fsub]) = ah;
        *(ushortx4*)(&AsL[row * 32 + fsub]) = al;
      }
    }
    glds16(Bh + bo0 + k0, &BsH[tid * 8]);
    glds16(Bh + bo1 + k0, &BsH[tid * 8 + 2048]);
    glds16(Bl + bo0 + k0, &BsL[tid * 8]);
    glds16(Bl + bo1 + k0, &BsL[tid * 8 + 2048]);
    __syncthreads();

    bf16x8 aH[4], aL[4], bH[4], bL[4];
#pragma unroll
    for (int i = 0; i < 4; ++i) {
      aH[i] = *(const bf16x8*)(&AsH[(wr + i * 16 + l16) * 32 + quad * 8]);
      aL[i] = *(const bf16x8*)(&AsL[(wr + i * 16 + l16) * 32 + quad * 8]);
    }
#pragma unroll
    for (int j = 0; j < 4; ++j) {
      bH[j] = *(const bf16x8*)(&BsH[(wc + j * 16 + l16) * 32 + quad * 8]);
      bL[j] = *(const bf16x8*)(&BsL[(wc + j * 16 + l16) * 32 + quad * 8]);
    }
#pragma unroll
    for (int i = 0; i < 4; ++i)
#pragma unroll
      for (int j = 0; j < 4; ++j)
        acc[i][j] = __builtin_amdgcn_mfma_f32_16x16x32_bf16(aL[i], bH[j], acc[i][j], 0, 0, 0);
#pragma unroll
    for (int i = 0; i < 4; ++i)
#pragma unroll
      for (int j = 0; j < 4; ++j)
        acc[i][j] = __builtin_amdgcn_mfma_f32_16x16x32_bf16(aH[i], bL[j], acc[i][j], 0, 0, 0);
#pragma unroll
    for (int i = 0; i < 4; ++i)
#pragma unroll
      for (int j = 0; j < 4; ++j)
        acc[i][j] = __builtin_amdgcn_mfma_f32_16x16x32_bf16(aH[i], bH[j], acc[i][j], 0, 0, 0);
  }

  // epilogue: lane = col l16; rows quad*4+r in each 16x16 sub-tile
#pragma unroll
  for (int j = 0; j < 4; ++j) {
    int col = n0 + wc + j * 16 + l16;
    float bv = (bias != nullptr) ? bias[col] : 0.f;
#pragma unroll
    for (int i = 0; i < 4; ++i) {
      int mbase = m0 + wr + i * 16 + quad * 4;
      if constexpr (MODE == 0) {
#pragma unroll
        for (int r = 0; r < 4; ++r)
          CoutF[(long)z * cBatch + (long)(mbase + r) * N + col] = acc[i][j][r] + bv;
      } else if constexpr (MODE == 1) {
#pragma unroll
        for (int r = 0; r < 4; ++r) {
          float f = acc[i][j][r] + bv;
          ushort_t h = f2b(f);
          long idx = (long)(mbase + r) * N + col;
          CoutH[idx] = h;
          CoutL[idx] = f2b(f - b2f(h));
        }
      } else {
        int b = mbase >> 10, jrow = mbase & 1023;
        ushortx4 ph, pl;
#pragma unroll
        for (int r = 0; r < 4; ++r) {
          float f = acc[i][j][r] + bv;
          ph[r] = f2b(f); pl[r] = f2b(f - b2f(ph[r]));
        }
        long idx = ((long)b * N + col) * 1024 + jrow;
        *(ushortx4*)(CoutH + idx) = ph;
        *(ushortx4*)(CoutL + idx) = pl;
      }
    }
  }
}

// =========================================================================
// split fp32 -> bf16 hi/lo planes. 8 elems/thread.
// =========================================================================
__global__ __launch_bounds__(256) void split_kernel(
    const float* __restrict__ src, ushort_t* __restrict__ hi,
    ushort_t* __restrict__ lo, long nvec)
{
  long i = (long)blockIdx.x * 256 + threadIdx.x;
  if (i >= nvec) return;
  floatx4 a = ((const floatx4*)src)[2 * i];
  floatx4 b = ((const floatx4*)src)[2 * i + 1];
  ushortx4 ha, hb, la, lb;
#pragma unroll
  for (int r = 0; r < 4; ++r) {
    ha[r] = f2b(a[r]); la[r] = f2b(a[r] - b2f(ha[r]));
    hb[r] = f2b(b[r]); lb[r] = f2b(b[r] - b2f(hb[r]));
  }
  ((ushortx4*)hi)[2 * i] = ha; ((ushortx4*)hi)[2 * i + 1] = hb;
  ((ushortx4*)lo)[2 * i] = la; ((ushortx4*)lo)[2 * i + 1] = lb;
}

// =========================================================================
// Attention over batch axis: per (n,h), q,k,v are (8 x 64). qkv as hi/lo.
// =========================================================================
__global__ __launch_bounds__(256) void attn_kernel(
    const ushort_t* __restrict__ qh, const ushort_t* __restrict__ ql,
    ushort_t* __restrict__ oh, ushort_t* __restrict__ ol)
{
  __shared__ float qs[4][8][65], ks[4][8][65], vs[4][8][65];
  __shared__ float aw[4][64];
  const int w    = threadIdx.x >> 6;
  const int lane = threadIdx.x & 63;
  const int p = blockIdx.x * 4 + w;
  const int n = p >> 3, h = p & 7;

  const long base = (long)n * 1536 + h * 64;
#pragma unroll
  for (int i = 0; i < 8; ++i) {
    long off = base + (long)i * 1024 * 1536;
    qs[w][i][lane] = b2f(qh[off + lane])        + b2f(ql[off + lane]);
    ks[w][i][lane] = b2f(qh[off + 512 + lane])  + b2f(ql[off + 512 + lane]);
    vs[w][i][lane] = b2f(qh[off + 1024 + lane]) + b2f(ql[off + 1024 + lane]);
  }
  __syncthreads();

  const int i = lane >> 3, j = lane & 7;
  float s = 0.f;
#pragma unroll 8
  for (int d = 0; d < 64; ++d) s += qs[w][i][d] * ks[w][j][d];
  s *= 0.125f;

  float m = s;
  m = fmaxf(m, __shfl_xor(m, 1));
  m = fmaxf(m, __shfl_xor(m, 2));
  m = fmaxf(m, __shfl_xor(m, 4));
  float e = __expf(s - m);
  float sum = e;
  sum += __shfl_xor(sum, 1);
  sum += __shfl_xor(sum, 2);
  sum += __shfl_xor(sum, 4);
  aw[w][lane] = e / sum;
  __syncthreads();

  const long ob = (long)n * 512 + h * 64 + lane;
#pragma unroll
  for (int ii = 0; ii < 8; ++ii) {
    float acc = 0.f;
#pragma unroll
    for (int jj = 0; jj < 8; ++jj) acc += aw[w][ii * 8 + jj] * vs[w][jj][lane];
    long idx = ob + (long)ii * 1024 * 512;
    ushort_t hh = f2b(acc);
    oh[idx] = hh; ol[idx] = f2b(acc - b2f(hh));
  }
}

// =========================================================================
// x_out = LayerNorm(hi+lo residual + agg). Wave per row (512).
// outF != null -> fp32 out; else hi/lo pair out (in-place on xh/xl ok).
// =========================================================================
__global__ __launch_bounds__(256) void ln_kernel(
    const ushort_t* __restrict__ xh, const ushort_t* __restrict__ xl,
    const float* __restrict__ agg, float* __restrict__ outF,
    ushort_t* __restrict__ outH, ushort_t* __restrict__ outL)
{
  const int w = threadIdx.x >> 6, lane = threadIdx.x & 63;
  const long base = ((long)blockIdx.x * 4 + w) * 512;
  float v[8];
  float s = 0.f;
#pragma unroll
  for (int k = 0; k < 8; ++k) {
    long idx = base + lane + 64 * k;
    v[k] = b2f(xh[idx]) + b2f(xl[idx]) + agg[idx];
    s += v[k];
  }
#pragma unroll
  for (int msk = 1; msk <= 32; msk <<= 1) s += __shfl_xor(s, msk);
  float mean = s * (1.f / 512.f);
  float vv = 0.f;
#pragma unroll
  for (int k = 0; k < 8; ++k) { float d = v[k] - mean; vv += d * d; }
#pragma unroll
  for (int msk = 1; msk <= 32; msk <<= 1) vv += __shfl_xor(vv, msk);
  float inv = rsqrtf(vv * (1.f / 512.f) + 1e-5f);
#pragma unroll
  for (int k = 0; k < 8; ++k) {
    long idx = base + lane + 64 * k;
    float val = (v[k] - mean) * inv;
    if (outF) outF[idx] = val;
    else { ushort_t h = f2b(val); outH[idx] = h; outL[idx] = f2b(val - b2f(h)); }
  }
}

// =========================================================================
// Heads: per row of x (8192x512): mastery(1), diff(5), h1, h2. Wave/row.
// =========================================================================
__global__ __launch_bounds__(256) void heads_kernel(
    const float* __restrict__ x,
    const float* __restrict__ Wcls, const float* __restrict__ bcls,
    const float* __restrict__ Wdiff, const float* __restrict__ bdiff,
    const float* __restrict__ Wpre,
    float* __restrict__ mastery, float* __restrict__ diff,
    float* __restrict__ h1, float* __restrict__ h2)
{
  const int w = threadIdx.x >> 6, lane = threadIdx.x & 63;
  const long row = (long)blockIdx.x * 4 + w;
  float xv[8];
#pragma unroll
  for (int k = 0; k < 8; ++k) xv[k] = x[row * 512 + lane + 64 * k];

#pragma unroll
  for (int o = 0; o < 8; ++o) {
    const float* wp = (o == 0) ? Wcls
                    : (o <= 5) ? (Wdiff + (o - 1) * 512)
                    : (o == 6) ? Wpre : (Wpre + 512);
    float p = 0.f;
#pragma unroll
    for (int k = 0; k < 8; ++k) p += xv[k] * wp[lane + 64 * k];
#pragma unroll
    for (int msk = 1; msk <= 32; msk <<= 1) p += __shfl_xor(p, msk);
    if (lane == 0) {
      if (o == 0)      mastery[row] = p + bcls[0];
      else if (o <= 5) diff[row * 5 + (o - 1)] = p + bdiff[o - 1];
      else if (o == 6) h1[row] = p;
      else             h2[row] = p;
    }
  }
}

__global__ __launch_bounds__(256) void prereq_kernel(
    const float* __restrict__ h1, const float* __restrict__ h2,
    const float* __restrict__ bpre, float* __restrict__ outp)
{
  const int b = blockIdx.y, i = blockIdx.x;
  const float base = h1[b * 1024 + i] + bpre[0];
  const long ob = (long)b * (1024 * 1023) + (long)i * 1023;
#pragma unroll
  for (int r = 0; r < 4; ++r) {
    int j = r * 256 + threadIdx.x;
    if (j == i) continue;
    int pos = (j < i) ? j : j - 1;
    outp[ob + pos] = base + h2[b * 1024 + j];
  }
}

__global__ __launch_bounds__(256) void zero_kernel(float* __restrict__ p) {
  p[blockIdx.x * 256 + threadIdx.x] = 0.f;
}

// xm[b,c] += sum over 64 n's (grid 256 = 8b x 2cc x 16ns); xm holds SUMS
__global__ __launch_bounds__(256) void pool_kernel(
    const float* __restrict__ x, float* __restrict__ xm)
{
  const int b = blockIdx.x >> 5, cc = (blockIdx.x >> 4) & 1, ns = blockIdx.x & 15;
  const int c = cc * 256 + threadIdx.x;
  float s = 0.f;
  for (int n = ns * 64; n < ns * 64 + 64; ++n)
    s += x[((long)b * 1024 + n) * 512 + c];
  atomicAdd(&xm[b * 512 + c], s);
}

// graph[b,o] = (xm[b]/1024) . Wpool[o] + b_pool[o]
__global__ __launch_bounds__(256) void graph_kernel(
    const float* __restrict__ xm, const float* __restrict__ Wpool,
    const float* __restrict__ bpool, float* __restrict__ g)
{
  const int gi = blockIdx.x * 256 + threadIdx.x;
  const int b = gi >> 9, o = gi & 511;
  float s = 0.f;
  for (int hh = 0; hh < 512; ++hh) s += xm[b * 512 + hh] * Wpool[o * 512 + hh];
  g[gi] = s * (1.f / 1024.f) + bpool[o];
}

// =========================================================================
extern "C" void kernel_launch(void* const* d_in, const int* in_sizes, int n_in,
                              void* d_out, int out_size, void* d_ws, size_t ws_size,
                              hipStream_t stream)
{
  const float* CF    = (const float*)d_in[0];
  const float* ADJ   = (const float*)d_in[1];
  const float* Wemb  = (const float*)d_in[4];
  const float* bemb  = (const float*)d_in[5];
  const float* Win   = (const float*)d_in[6];
  const float* bin   = (const float*)d_in[7];
  const float* Wout  = (const float*)d_in[8];
  const float* bout  = (const float*)d_in[9];
  const float* Wconv = (const float*)d_in[10];
  const float* bconv = (const float*)d_in[11];
  const float* Wcls  = (const float*)d_in[12];
  const float* bcls  = (const float*)d_in[13];
  const float* Wdiff = (const float*)d_in[14];
  const float* bdiff = (const float*)d_in[15];
  const float* Wpre  = (const float*)d_in[16];
  const float* bpre  = (const float*)d_in[17];
  const float* Wpool = (const float*)d_in[18];
  const float* bpool = (const float*)d_in[19];

  // ---- workspace layout (ushort units; total ~83.5 MB, <= round-2's 84) ----
  ushort_t* xh     = (ushort_t*)d_ws;          // 4194304
  ushort_t* xl     = xh + 4194304;
  ushort_t* qkvh   = xl + 4194304;             // 12582912
  ushort_t* qkvl   = qkvh + 12582912;
  // att/convT pairs alias the (dead-after-attn) qkv region:
  ushort_t* atth   = qkvh;
  ushort_t* attl   = atth + 4194304;
  ushort_t* cTh    = attl + 4194304;
  ushort_t* cTl    = cTh + 4194304;            // 16.7M <= 25.1M of region
  ushort_t* Wembh  = qkvl + 12582912;          // 131072
  ushort_t* Wembl  = Wembh + 131072;
  ushort_t* Winh   = Wembl + 131072;           // 2359296
  ushort_t* Winl   = Winh + 2359296;
  ushort_t* Wouth  = Winl + 2359296;           // 786432
  ushort_t* Woutl  = Wouth + 786432;
  ushort_t* Wconvh = Woutl + 786432;           // 786432
  ushort_t* Wconvl = Wconvh + 786432;
  float*    h1     = (float*)(Wconvl + 786432);// 8192
  float*    h2     = h1 + 8192;                // 8192
  float*    xm     = h2 + 8192;                // 4096

  // ---- output layout (fp32 concat) + d_out-as-scratch aliases ----
  float* out_x       = (float*)d_out;          // 4194304
  float* out_mastery = out_x + 4194304;        // 8192
  float* out_diff    = out_mastery + 8192;     // 40960
  float* out_prereq  = out_diff + 40960;       // 8380416
  float* out_graph   = out_prereq + 8380416;   // 4096
  // attn-out pair lives in out_x region (dead until final ln writes it):
  ushort_t* aoh = (ushort_t*)out_x;            // 4194304
  ushort_t* aol = aoh + 4194304;
  // agg lives in out_prereq region (written only at the very end):
  float* agg = out_prereq;                     // 4194304 floats <= 8380416

  dim3 blk(256);

  // weight splits (once per launch)
  split_kernel<<<dim3(64),   blk, 0, stream>>>(Wemb,  Wembh,  Wembl,  16384);
  split_kernel<<<dim3(1152), blk, 0, stream>>>(Win,   Winh,   Winl,   294912);
  split_kernel<<<dim3(384),  blk, 0, stream>>>(Wout,  Wouth,  Woutl,  98304);
  split_kernel<<<dim3(384),  blk, 0, stream>>>(Wconv, Wconvh, Wconvl, 98304);
  zero_kernel<<<dim3(16), blk, 0, stream>>>(xm);

  // x0 = CF @ Wemb^T + bemb  -> hi/lo pair   (8192 x 512 x 256, A fp32)
  gemm_bt<1, false><<<dim3(4, 64, 1), blk, 0, stream>>>(
      CF, nullptr, Wembh, Wembl, bemb, nullptr, xh, xl, 8192, 512, 256, 0, 0, 0);

  for (int l = 0; l < 3; ++l) {
    // qkv = x @ Win[l]^T + bin[l]  -> pair   (8192 x 1536 x 512)
    gemm_bt<1, true><<<dim3(12, 64, 1), blk, 0, stream>>>(
        xh, xl, Winh + (long)l * 786432, Winl + (long)l * 786432,
        bin + l * 1536, nullptr, qkvh, qkvl, 8192, 1536, 512, 0, 0, 0);
    // attention over batch axis -> ao pair (in out_x scratch)
    attn_kernel<<<dim3(2048), blk, 0, stream>>>(qkvh, qkvl, aoh, aol);
    // att = ao @ Wout[l]^T + bout[l] -> pair (aliases dead qkv)
    gemm_bt<1, true><<<dim3(4, 64, 1), blk, 0, stream>>>(
        aoh, aol, Wouth + (long)l * 262144, Woutl + (long)l * 262144,
        bout + l * 512, nullptr, atth, attl, 8192, 512, 512, 0, 0, 0);
    // convT = (att @ Wconv[l]^T + bconv[l]) transposed pair
    gemm_bt<2, true><<<dim3(4, 64, 1), blk, 0, stream>>>(
        atth, attl, Wconvh + (long)l * 262144, Wconvl + (long)l * 262144,
        bconv + l * 512, nullptr, cTh, cTl, 8192, 512, 512, 0, 0, 0);
    // agg[b] = adj[b] @ conv[b]  (batched 1024x512x1024, A fp32 hybrid)
    gemm_bt<0, false><<<dim3(4, 8, 8), blk, 0, stream>>>(
        ADJ, nullptr, cTh, cTl, nullptr, agg, nullptr, nullptr,
        1024, 512, 1024, 1048576, 524288, 524288);
    // x = LN(x + agg): pair out for l<2, fp32 out_x for l==2
    if (l < 2)
      ln_kernel<<<dim3(2048), blk, 0, stream>>>(xh, xl, agg, nullptr, xh, xl);
    else
      ln_kernel<<<dim3(2048), blk, 0, stream>>>(xh, xl, agg, out_x, nullptr, nullptr);
  }

  heads_kernel<<<dim3(2048), blk, 0, stream>>>(out_x, Wcls, bcls, Wdiff, bdiff,
                                               Wpre, out_mastery, out_diff, h1, h2);
  prereq_kernel<<<dim3(1024, 8), blk, 0, stream>>>(h1, h2, bpre, out_prereq);
  pool_kernel<<<dim3(256), blk, 0, stream>>>(out_x, xm);
  graph_kernel<<<dim3(16), blk, 0, stream>>>(xm, Wpool, bpool, out_graph);
}

// Round 4
// 706.476 us; speedup vs baseline: 1.3322x; 1.1308x over previous
//
#include <hip/hip_runtime.h>
#include <hip/hip_bf16.h>

typedef unsigned short ushort_t;
typedef __attribute__((ext_vector_type(4))) float floatx4;
typedef __attribute__((ext_vector_type(8))) __bf16 bf16x8;
typedef __attribute__((ext_vector_type(4))) unsigned short ushortx4;

// ---------- bf16 helpers ----------
static __device__ __forceinline__ float b2f(ushort_t u) {
  union { unsigned int i; float f; } v; v.i = ((unsigned int)u) << 16; return v.f;
}
static __device__ __forceinline__ ushort_t f2b(float f) {
  unsigned int x = __float_as_uint(f);
  unsigned int r = (x + 0x7fffu + ((x >> 16) & 1u)) >> 16;
  return (ushort_t)r;
}
// async global->LDS, 16B per lane (dest = wave-uniform base + lane*16)
static __device__ __forceinline__ void glds16(const ushort_t* g, ushort_t* l) {
  __builtin_amdgcn_global_load_lds(
      (const __attribute__((address_space(1))) unsigned int*)g,
      (__attribute__((address_space(3))) unsigned int*)l, 16, 0, 0);
}

// =========================================================================
// GEMM: C[M,N] = A[M,K] @ B[N,K]^T (+bias[col]).  bf16 hi/lo 3-pass MFMA.
// B always pre-split pair, staged via global_load_lds.
// ASPLIT: A pre-split pair (glds16) vs fp32 (in-kernel split).
// SPLITK: gridDim.z = 2*z; khalf = blockIdx.z&1 computes K/2 slice, writes
//         CoutF (half 0) or CoutF2 (half 1).  (MODE 0 only)
// MODE 0: fp32 row-major (+z*cBatch)
// MODE 1: bf16 hi/lo pair row-major (+z*cBatch)
// MODE 2: pair TRANSPOSED batched: [(b*N+col)*1024 + (m&1023)], b=m>>10
// Block 256 = 4 waves; tile 128x128; wave 64x64 via 4x4 mfma 16x16x32.
// =========================================================================
template<int MODE, bool ASPLIT, bool SPLITK>
__global__ __launch_bounds__(256, 2) void gemm_bt(
    const void* __restrict__ Ap, const ushort_t* __restrict__ Alo,
    const ushort_t* __restrict__ Bh, const ushort_t* __restrict__ Bl,
    const float* __restrict__ bias,
    float* __restrict__ CoutF, float* __restrict__ CoutF2,
    ushort_t* __restrict__ CoutH, ushort_t* __restrict__ CoutL,
    int M, int N, int K, long aBatch, long bBatch, long cBatch)
{
  __shared__ __align__(16) ushort_t AsH[128 * 32];
  __shared__ __align__(16) ushort_t AsL[128 * 32];
  __shared__ __align__(16) ushort_t BsH[128 * 32];
  __shared__ __align__(16) ushort_t BsL[128 * 32];

  const int tid  = threadIdx.x;
  const int wid  = tid >> 6;
  const int lane = tid & 63;
  const int quad = lane >> 4;
  const int l16  = lane & 15;
  const int m0 = blockIdx.y * 128;
  const int n0 = blockIdx.x * 128;
  const int z  = SPLITK ? (blockIdx.z >> 1) : blockIdx.z;
  const int kh = SPLITK ? (blockIdx.z & 1) : 0;
  const int kbeg = SPLITK ? kh * (K >> 1) : 0;
  const int kend = SPLITK ? kbeg + (K >> 1) : K;
  float* outF = (SPLITK && kh) ? CoutF2 : CoutF;

  const ushort_t* Ah = (const ushort_t*)Ap + (long)z * aBatch;
  const ushort_t* Al = Alo ? (Alo + (long)z * aBatch) : nullptr;
  const float*    Af = (const float*)Ap + (long)z * aBatch;
  Bh += (long)z * bBatch;
  Bl += (long)z * bBatch;

  const int wr = (wid >> 1) * 64;
  const int wc = (wid & 1) * 64;

  const int srow = tid >> 2, ssub = (tid & 3) * 8;
  const long ao0 = (long)(m0 + srow) * K + ssub, ao1 = ao0 + 64 * (long)K;
  const long bo0 = (long)(n0 + srow) * K + ssub, bo1 = bo0 + 64 * (long)K;
  const int frow = tid >> 3, fsub = (tid & 7) * 4;   // fp32 A path

  floatx4 acc[4][4];
#pragma unroll
  for (int i = 0; i < 4; ++i)
#pragma unroll
    for (int j = 0; j < 4; ++j) acc[i][j] = (floatx4){0.f, 0.f, 0.f, 0.f};

  for (int k0 = kbeg; k0 < kend; k0 += 32) {
    __syncthreads();
    if constexpr (ASPLIT) {
      glds16(Ah + ao0 + k0, &AsH[tid * 8]);
      glds16(Ah + ao1 + k0, &AsH[tid * 8 + 2048]);
      glds16(Al + ao0 + k0, &AsL[tid * 8]);
      glds16(Al + ao1 + k0, &AsL[tid * 8 + 2048]);
    } else {
#pragma unroll
      for (int p = 0; p < 4; ++p) {
        int row = frow + p * 32;
        floatx4 va = *(const floatx4*)(Af + (long)(m0 + row) * K + k0 + fsub);
        ushortx4 ah, al;
#pragma unroll
        for (int r = 0; r < 4; ++r) {
          ah[r] = f2b(va[r]); al[r] = f2b(va[r] - b2f(ah[r]));
        }
        *(ushortx4*)(&AsH[row * 32 + fsub]) = ah;
        *(ushortx4*)(&AsL[row * 32 + fsub]) = al;
      }
    }
    glds16(Bh + bo0 + k0, &BsH[tid * 8]);
    glds16(Bh + bo1 + k0, &BsH[tid * 8 + 2048]);
    glds16(Bl + bo0 + k0, &BsL[tid * 8]);
    glds16(Bl + bo1 + k0, &BsL[tid * 8 + 2048]);
    __syncthreads();

    bf16x8 aH[4], aL[4], bH[4], bL[4];
#pragma unroll
    for (int i = 0; i < 4; ++i) {
      aH[i] = *(const bf16x8*)(&AsH[(wr + i * 16 + l16) * 32 + quad * 8]);
      aL[i] = *(const bf16x8*)(&AsL[(wr + i * 16 + l16) * 32 + quad * 8]);
    }
#pragma unroll
    for (int j = 0; j < 4; ++j) {
      bH[j] = *(const bf16x8*)(&BsH[(wc + j * 16 + l16) * 32 + quad * 8]);
      bL[j] = *(const bf16x8*)(&BsL[(wc + j * 16 + l16) * 32 + quad * 8]);
    }
#pragma unroll
    for (int i = 0; i < 4; ++i)
#pragma unroll
      for (int j = 0; j < 4; ++j)
        acc[i][j] = __builtin_amdgcn_mfma_f32_16x16x32_bf16(aL[i], bH[j], acc[i][j], 0, 0, 0);
#pragma unroll
    for (int i = 0; i < 4; ++i)
#pragma unroll
      for (int j = 0; j < 4; ++j)
        acc[i][j] = __builtin_amdgcn_mfma_f32_16x16x32_bf16(aH[i], bL[j], acc[i][j], 0, 0, 0);
#pragma unroll
    for (int i = 0; i < 4; ++i)
#pragma unroll
      for (int j = 0; j < 4; ++j)
        acc[i][j] = __builtin_amdgcn_mfma_f32_16x16x32_bf16(aH[i], bH[j], acc[i][j], 0, 0, 0);
  }

  // epilogue: lane = col l16; rows quad*4+r in each 16x16 sub-tile
#pragma unroll
  for (int j = 0; j < 4; ++j) {
    int col = n0 + wc + j * 16 + l16;
    float bv = (bias != nullptr) ? bias[col] : 0.f;
#pragma unroll
    for (int i = 0; i < 4; ++i) {
      int mbase = m0 + wr + i * 16 + quad * 4;
      if constexpr (MODE == 0) {
#pragma unroll
        for (int r = 0; r < 4; ++r)
          outF[(long)z * cBatch + (long)(mbase + r) * N + col] = acc[i][j][r] + bv;
      } else if constexpr (MODE == 1) {
#pragma unroll
        for (int r = 0; r < 4; ++r) {
          float f = acc[i][j][r] + bv;
          ushort_t h = f2b(f);
          long idx = (long)z * cBatch + (long)(mbase + r) * N + col;
          CoutH[idx] = h;
          CoutL[idx] = f2b(f - b2f(h));
        }
      } else {
        int b = mbase >> 10, jrow = mbase & 1023;
        ushortx4 ph, pl;
#pragma unroll
        for (int r = 0; r < 4; ++r) {
          float f = acc[i][j][r] + bv;
          ph[r] = f2b(f); pl[r] = f2b(f - b2f(ph[r]));
        }
        long idx = ((long)b * N + col) * 1024 + jrow;
        *(ushortx4*)(CoutH + idx) = ph;
        *(ushortx4*)(CoutL + idx) = pl;
      }
    }
  }
}

// =========================================================================
// split fp32 -> bf16 hi/lo planes. 8 elems/thread.
// =========================================================================
__global__ __launch_bounds__(256) void split_kernel(
    const float* __restrict__ src, ushort_t* __restrict__ hi,
    ushort_t* __restrict__ lo, long nvec)
{
  long i = (long)blockIdx.x * 256 + threadIdx.x;
  if (i >= nvec) return;
  floatx4 a = ((const floatx4*)src)[2 * i];
  floatx4 b = ((const floatx4*)src)[2 * i + 1];
  ushortx4 ha, hb, la, lb;
#pragma unroll
  for (int r = 0; r < 4; ++r) {
    ha[r] = f2b(a[r]); la[r] = f2b(a[r] - b2f(ha[r]));
    hb[r] = f2b(b[r]); lb[r] = f2b(b[r] - b2f(hb[r]));
  }
  ((ushortx4*)hi)[2 * i] = ha; ((ushortx4*)hi)[2 * i + 1] = hb;
  ((ushortx4*)lo)[2 * i] = la; ((ushortx4*)lo)[2 * i + 1] = lb;
}

// =========================================================================
// transpose + split: WoT[l][k][j] = split(W[l][j][k]), 512x512 per l.
// grid (8 ktiles, 8 jtiles, 3); 64x64 tile per block.
// =========================================================================
__global__ __launch_bounds__(256) void transpose_split_kernel(
    const float* __restrict__ W, ushort_t* __restrict__ Th,
    ushort_t* __restrict__ Tl)
{
  __shared__ float tile[64][65];
  const int k0 = blockIdx.x * 64, j0 = blockIdx.y * 64;
  const long base = (long)blockIdx.z * 262144;
  const int tid = threadIdx.x;
#pragma unroll
  for (int p = 0; p < 16; ++p) {
    int idx = tid + p * 256;
    int jj = idx >> 6, kk = idx & 63;
    tile[jj][kk] = W[base + (long)(j0 + jj) * 512 + k0 + kk];
  }
  __syncthreads();
#pragma unroll
  for (int p = 0; p < 16; ++p) {
    int idx = tid + p * 256;
    int kk = idx >> 6, jj = idx & 63;
    float v = tile[jj][kk];
    ushort_t h = f2b(v);
    long o = base + (long)(k0 + kk) * 512 + j0 + jj;
    Th[o] = h; Tl[o] = f2b(v - b2f(h));
  }
}

// bfused[l][o] = dot(Wconv[l][o][:], bout[l][:]) + bconv[l][o].  wave/output.
__global__ __launch_bounds__(256) void bfuse_kernel(
    const float* __restrict__ Wconv, const float* __restrict__ bout,
    const float* __restrict__ bconv, float* __restrict__ bf)
{
  const int w = threadIdx.x >> 6, lane = threadIdx.x & 63;
  const int gi = blockIdx.x * 4 + w;           // 0..1535
  const int l = gi >> 9, o = gi & 511;
  float p = 0.f;
#pragma unroll
  for (int k = 0; k < 8; ++k)
    p += Wconv[(long)l * 262144 + (long)o * 512 + lane + 64 * k] *
         bout[l * 512 + lane + 64 * k];
#pragma unroll
  for (int msk = 1; msk <= 32; msk <<= 1) p += __shfl_xor(p, msk);
  if (lane == 0) bf[gi] = p + bconv[l * 512 + o];
}

// =========================================================================
// Attention over batch axis: per (n,h), q,k,v are (8 x 64). qkv as hi/lo.
// =========================================================================
__global__ __launch_bounds__(256) void attn_kernel(
    const ushort_t* __restrict__ qh, const ushort_t* __restrict__ ql,
    ushort_t* __restrict__ oh, ushort_t* __restrict__ ol)
{
  __shared__ float qs[4][8][65], ks[4][8][65], vs[4][8][65];
  __shared__ float aw[4][64];
  const int w    = threadIdx.x >> 6;
  const int lane = threadIdx.x & 63;
  const int p = blockIdx.x * 4 + w;
  const int n = p >> 3, h = p & 7;

  const long base = (long)n * 1536 + h * 64;
#pragma unroll
  for (int i = 0; i < 8; ++i) {
    long off = base + (long)i * 1024 * 1536;
    qs[w][i][lane] = b2f(qh[off + lane])        + b2f(ql[off + lane]);
    ks[w][i][lane] = b2f(qh[off + 512 + lane])  + b2f(ql[off + 512 + lane]);
    vs[w][i][lane] = b2f(qh[off + 1024 + lane]) + b2f(ql[off + 1024 + lane]);
  }
  __syncthreads();

  const int i = lane >> 3, j = lane & 7;
  float s = 0.f;
#pragma unroll 8
  for (int d = 0; d < 64; ++d) s += qs[w][i][d] * ks[w][j][d];
  s *= 0.125f;

  float m = s;
  m = fmaxf(m, __shfl_xor(m, 1));
  m = fmaxf(m, __shfl_xor(m, 2));
  m = fmaxf(m, __shfl_xor(m, 4));
  float e = __expf(s - m);
  float sum = e;
  sum += __shfl_xor(sum, 1);
  sum += __shfl_xor(sum, 2);
  sum += __shfl_xor(sum, 4);
  aw[w][lane] = e / sum;
  __syncthreads();

  const long ob = (long)n * 512 + h * 64 + lane;
#pragma unroll
  for (int ii = 0; ii < 8; ++ii) {
    float acc = 0.f;
#pragma unroll
    for (int jj = 0; jj < 8; ++jj) acc += aw[w][ii * 8 + jj] * vs[w][jj][lane];
    long idx = ob + (long)ii * 1024 * 512;
    ushort_t hh = f2b(acc);
    oh[idx] = hh; ol[idx] = f2b(acc - b2f(hh));
  }
}

// =========================================================================
// x_out = LayerNorm(hi+lo residual + agg1 + agg2). Wave per row (512).
// =========================================================================
__global__ __launch_bounds__(256) void ln_kernel(
    const ushort_t* __restrict__ xh, const ushort_t* __restrict__ xl,
    const float* __restrict__ agg1, const float* __restrict__ agg2,
    float* __restrict__ outF,
    ushort_t* __restrict__ outH, ushort_t* __restrict__ outL)
{
  const int w = threadIdx.x >> 6, lane = threadIdx.x & 63;
  const long base = ((long)blockIdx.x * 4 + w) * 512;
  float v[8];
  float s = 0.f;
#pragma unroll
  for (int k = 0; k < 8; ++k) {
    long idx = base + lane + 64 * k;
    v[k] = b2f(xh[idx]) + b2f(xl[idx]) + agg1[idx] + agg2[idx];
    s += v[k];
  }
#pragma unroll
  for (int msk = 1; msk <= 32; msk <<= 1) s += __shfl_xor(s, msk);
  float mean = s * (1.f / 512.f);
  float vv = 0.f;
#pragma unroll
  for (int k = 0; k < 8; ++k) { float d = v[k] - mean; vv += d * d; }
#pragma unroll
  for (int msk = 1; msk <= 32; msk <<= 1) vv += __shfl_xor(vv, msk);
  float inv = rsqrtf(vv * (1.f / 512.f) + 1e-5f);
#pragma unroll
  for (int k = 0; k < 8; ++k) {
    long idx = base + lane + 64 * k;
    float val = (v[k] - mean) * inv;
    if (outF) outF[idx] = val;
    else { ushort_t h = f2b(val); outH[idx] = h; outL[idx] = f2b(val - b2f(h)); }
  }
}

// =========================================================================
// Heads: per row of x (8192x512): mastery(1), diff(5), h1, h2. Wave/row.
// =========================================================================
__global__ __launch_bounds__(256) void heads_kernel(
    const float* __restrict__ x,
    const float* __restrict__ Wcls, const float* __restrict__ bcls,
    const float* __restrict__ Wdiff, const float* __restrict__ bdiff,
    const float* __restrict__ Wpre,
    float* __restrict__ mastery, float* __restrict__ diff,
    float* __restrict__ h1, float* __restrict__ h2)
{
  const int w = threadIdx.x >> 6, lane = threadIdx.x & 63;
  const long row = (long)blockIdx.x * 4 + w;
  float xv[8];
#pragma unroll
  for (int k = 0; k < 8; ++k) xv[k] = x[row * 512 + lane + 64 * k];

#pragma unroll
  for (int o = 0; o < 8; ++o) {
    const float* wp = (o == 0) ? Wcls
                    : (o <= 5) ? (Wdiff + (o - 1) * 512)
                    : (o == 6) ? Wpre : (Wpre + 512);
    float p = 0.f;
#pragma unroll
    for (int k = 0; k < 8; ++k) p += xv[k] * wp[lane + 64 * k];
#pragma unroll
    for (int msk = 1; msk <= 32; msk <<= 1) p += __shfl_xor(p, msk);
    if (lane == 0) {
      if (o == 0)      mastery[row] = p + bcls[0];
      else if (o <= 5) diff[row * 5 + (o - 1)] = p + bdiff[o - 1];
      else if (o == 6) h1[row] = p;
      else             h2[row] = p;
    }
  }
}

__global__ __launch_bounds__(256) void prereq_kernel(
    const float* __restrict__ h1, const float* __restrict__ h2,
    const float* __restrict__ bpre, float* __restrict__ outp)
{
  const int b = blockIdx.y, i = blockIdx.x;
  const float base = h1[b * 1024 + i] + bpre[0];
  const long ob = (long)b * (1024 * 1023) + (long)i * 1023;
#pragma unroll
  for (int r = 0; r < 4; ++r) {
    int j = r * 256 + threadIdx.x;
    if (j == i) continue;
    int pos = (j < i) ? j : j - 1;
    outp[ob + pos] = base + h2[b * 1024 + j];
  }
}

__global__ __launch_bounds__(256) void zero_kernel(float* __restrict__ p) {
  p[blockIdx.x * 256 + threadIdx.x] = 0.f;
}

// xm[b,c] += partial sums (grid 256 = 8b x 2cc x 16ns); xm holds SUMS
__global__ __launch_bounds__(256) void pool_kernel(
    const float* __restrict__ x, float* __restrict__ xm)
{
  const int b = blockIdx.x >> 5, cc = (blockIdx.x >> 4) & 1, ns = blockIdx.x & 15;
  const int c = cc * 256 + threadIdx.x;
  float s = 0.f;
  for (int n = ns * 64; n < ns * 64 + 64; ++n)
    s += x[((long)b * 1024 + n) * 512 + c];
  atomicAdd(&xm[b * 512 + c], s);
}

// graph[b,o] = (xm[b]/1024) . Wpool[o] + b_pool[o]
__global__ __launch_bounds__(256) void graph_kernel(
    const float* __restrict__ xm, const float* __restrict__ Wpool,
    const float* __restrict__ bpool, float* __restrict__ g)
{
  const int gi = blockIdx.x * 256 + threadIdx.x;
  const int b = gi >> 9, o = gi & 511;
  float s = 0.f;
  for (int hh = 0; hh < 512; ++hh) s += xm[b * 512 + hh] * Wpool[o * 512 + hh];
  g[gi] = s * (1.f / 1024.f) + bpool[o];
}

// =========================================================================
extern "C" void kernel_launch(void* const* d_in, const int* in_sizes, int n_in,
                              void* d_out, int out_size, void* d_ws, size_t ws_size,
                              hipStream_t stream)
{
  const float* CF    = (const float*)d_in[0];
  const float* ADJ   = (const float*)d_in[1];
  const float* Wemb  = (const float*)d_in[4];
  const float* bemb  = (const float*)d_in[5];
  const float* Win   = (const float*)d_in[6];
  const float* bin   = (const float*)d_in[7];
  const float* Wout  = (const float*)d_in[8];
  const float* bout  = (const float*)d_in[9];
  const float* Wconv = (const float*)d_in[10];
  const float* bconv = (const float*)d_in[11];
  const float* Wcls  = (const float*)d_in[12];
  const float* bcls  = (const float*)d_in[13];
  const float* Wdiff = (const float*)d_in[14];
  const float* bdiff = (const float*)d_in[15];
  const float* Wpre  = (const float*)d_in[16];
  const float* bpre  = (const float*)d_in[17];
  const float* Wpool = (const float*)d_in[18];
  const float* bpool = (const float*)d_in[19];

  // ---- workspace layout (ushort offsets). Base ~83 MB (round-3 proven). ----
  ushort_t* W = (ushort_t*)d_ws;
  ushort_t* xh   = W;                       // 4194304
  ushort_t* xl   = W + 4194304;
  ushort_t* qkvh = W + 8388608;             // 12582912
  ushort_t* qkvl = W + 20971520;            // 12582912 (region end 33554432)
  // conv-out transposed pair aliases the (dead-after-attn) qkv region:
  ushort_t* cTh  = qkvh;
  ushort_t* cTl  = qkvh + 4194304;
  // precompute scratch in qkv region (dead before first qkv GEMM):
  ushort_t* WoTh  = qkvh + 8388608;         // 786432  (WoutT pair, all layers)
  ushort_t* WoTl  = WoTh + 786432;
  ushort_t* Wembh = WoTl + 786432;          // 131072
  ushort_t* Wembl = Wembh + 131072;         // end qkvh+10223616 < 12582912 ok
  // persistent weight pairs:
  ushort_t* Winh = W + 33554432;            // 2359296
  ushort_t* Winl = Winh + 2359296;
  ushort_t* Wfh  = Winl + 2359296;          // 786432 (fused Wconv@Wout pair)
  ushort_t* Wfl  = Wfh + 786432;            // end 40632320 u
  float* bfused = (float*)(W + 40632320);   // 1536
  float* h1     = bfused + 1536;            // 8192
  float* h2     = h1 + 8192;                // 8192
  float* xm     = h2 + 8192;                // 4096
  // optional pre-split ADJ pair (33.5 MB) — gated on ws_size:
  ushort_t* ADJh = W + 40676352;            // 8388608 (16B-aligned offset)
  ushort_t* ADJl = ADJh + 8388608;          // end 57453568 u = 114.9 MB
  const bool adjPre = ws_size >= (size_t)57453568 * 2 + 1024;

  // ---- output layout (fp32 concat) + d_out-as-scratch aliases ----
  float* out_x       = (float*)d_out;       // 4194304
  float* out_mastery = out_x + 4194304;     // 8192
  float* out_diff    = out_mastery + 8192;  // 40960
  float* out_prereq  = out_diff + 40960;    // 8380416
  float* out_graph   = out_prereq + 8380416;// 4096
  // attn-out pair in out_x region (dead until final ln writes it):
  ushort_t* aoh = (ushort_t*)out_x;         // 4194304
  ushort_t* aol = aoh + 4194304;
  // split-K partial buffers: agg1 in prereq region, agg2 in out_x region
  // (ao pair is dead by adjacency-GEMM time; ln reads agg2 before writing
  //  out_x element-wise at l==2 — same-thread read-before-write, safe).
  float* agg1 = out_prereq;                 // 4194304 floats
  float* agg2 = out_x;                      // 4194304 floats

  dim3 blk(256);

  // ---- precompute (once per launch) ----
  split_kernel<<<dim3(1152), blk, 0, stream>>>(Win,  Winh,  Winl,  294912);
  split_kernel<<<dim3(64),   blk, 0, stream>>>(Wemb, Wembh, Wembl, 16384);
  transpose_split_kernel<<<dim3(8, 8, 3), blk, 0, stream>>>(Wout, WoTh, WoTl);
  // Wconv pair: stage temporarily in cT region (dead until layer-0 conv GEMM)
  ushort_t* Wch = cTh;           // 786432 fits in cT region (4194304)
  ushort_t* Wcl = cTh + 786432;
  split_kernel<<<dim3(384), blk, 0, stream>>>(Wconv, Wch, Wcl, 98304);
  // Wfused[l] = Wconv[l] @ Wout[l]  (batched z=3, 512x512x512)
  gemm_bt<1, true, false><<<dim3(4, 4, 3), blk, 0, stream>>>(
      Wch, Wcl, WoTh, WoTl, nullptr, nullptr, nullptr, Wfh, Wfl,
      512, 512, 512, 262144, 262144, 262144);
  bfuse_kernel<<<dim3(384), blk, 0, stream>>>(Wconv, bout, bconv, bfused);
  if (adjPre)
    split_kernel<<<dim3(4096), blk, 0, stream>>>(ADJ, ADJh, ADJl, 1048576);
  zero_kernel<<<dim3(16), blk, 0, stream>>>(xm);

  // x0 = CF @ Wemb^T + bemb  -> hi/lo pair   (8192 x 512 x 256, A fp32)
  gemm_bt<1, false, false><<<dim3(4, 64, 1), blk, 0, stream>>>(
      CF, nullptr, Wembh, Wembl, bemb, nullptr, nullptr, xh, xl,
      8192, 512, 256, 0, 0, 0);

  for (int l = 0; l < 3; ++l) {
    // qkv = x @ Win[l]^T + bin[l]  -> pair   (8192 x 1536 x 512)
    gemm_bt<1, true, false><<<dim3(12, 64, 1), blk, 0, stream>>>(
        xh, xl, Winh + (long)l * 786432, Winl + (long)l * 786432,
        bin + l * 1536, nullptr, nullptr, qkvh, qkvl, 8192, 1536, 512, 0, 0, 0);
    // attention over batch axis -> ao pair (out_x scratch)
    attn_kernel<<<dim3(2048), blk, 0, stream>>>(qkvh, qkvl, aoh, aol);
    // convT = (ao @ Wfused[l]^T + bfused[l]) transposed pair (qkv dead)
    gemm_bt<2, true, false><<<dim3(4, 64, 1), blk, 0, stream>>>(
        aoh, aol, Wfh + (long)l * 262144, Wfl + (long)l * 262144,
        bfused + l * 512, nullptr, nullptr, cTh, cTl, 8192, 512, 512, 0, 0, 0);
    // agg[b] = adj[b] @ conv[b]  (batched 1024x512x1024, split-K=2)
    if (adjPre)
      gemm_bt<0, true, true><<<dim3(4, 8, 16), blk, 0, stream>>>(
          ADJh, ADJl, cTh, cTl, nullptr, agg1, agg2, nullptr, nullptr,
          1024, 512, 1024, 1048576, 524288, 524288);
    else
      gemm_bt<0, false, true><<<dim3(4, 8, 16), blk, 0, stream>>>(
          ADJ, nullptr, cTh, cTl, nullptr, agg1, agg2, nullptr, nullptr,
          1024, 512, 1024, 1048576, 524288, 524288);
    // x = LN(x + agg1 + agg2): pair out for l<2, fp32 out_x for l==2
    if (l < 2)
      ln_kernel<<<dim3(2048), blk, 0, stream>>>(xh, xl, agg1, agg2,
                                                nullptr, xh, xl);
    else
      ln_kernel<<<dim3(2048), blk, 0, stream>>>(xh, xl, agg1, agg2,
                                                out_x, nullptr, nullptr);
  }

  heads_kernel<<<dim3(2048), blk, 0, stream>>>(out_x, Wcls, bcls, Wdiff, bdiff,
                                               Wpre, out_mastery, out_diff, h1, h2);
  prereq_kernel<<<dim3(1024, 8), blk, 0, stream>>>(h1, h2, bpre, out_prereq);
  pool_kernel<<<dim3(256), blk, 0, stream>>>(out_x, xm);
  graph_kernel<<<dim3(16), blk, 0, stream>>>(xm, Wpool, bpool, out_graph);
}

// Round 5
// 487.949 us; speedup vs baseline: 1.9288x; 1.4479x over previous
//
#include <hip/hip_runtime.h>
#include <hip/hip_bf16.h>

typedef unsigned short ushort_t;
typedef __attribute__((ext_vector_type(4))) float floatx4;
typedef __attribute__((ext_vector_type(8))) __bf16 bf16x8;
typedef __attribute__((ext_vector_type(4))) unsigned short ushortx4;

// ---------- bf16 helpers ----------
static __device__ __forceinline__ float b2f(ushort_t u) {
  union { unsigned int i; float f; } v; v.i = ((unsigned int)u) << 16; return v.f;
}
static __device__ __forceinline__ ushort_t f2b(float f) {
  unsigned int x = __float_as_uint(f);
  unsigned int r = (x + 0x7fffu + ((x >> 16) & 1u)) >> 16;
  return (ushort_t)r;
}
// async global->LDS, 16B per lane (dest = wave-uniform base + lane*16)
static __device__ __forceinline__ void glds16(const ushort_t* g, ushort_t* l) {
  __builtin_amdgcn_global_load_lds(
      (const __attribute__((address_space(1))) unsigned int*)g,
      (__attribute__((address_space(3))) unsigned int*)l, 16, 0, 0);
}

// =========================================================================
// GEMM: C[M,N] = A[M,K] @ B[N,K]^T (+bias[col]).  Single-plane bf16 MFMA.
// B always bf16 (k-contig), staged via global_load_lds.
// ASPLIT: A bf16 (glds16) vs fp32 (in-kernel convert).
// SPLITK: gridDim.z = 2*z; blockIdx.z&1 selects K/2 slice; half 0 -> CoutF,
//         half 1 -> CoutF2 (MODE 0 only).
// MODE 0: fp32 row-major (+z*cBatch)
// MODE 1: bf16 row-major (+z*cBatch)
// MODE 2: bf16 TRANSPOSED batched: [(b*N+col)*1024 + (m&1023)], b=m>>10
// Block 256 = 4 waves; tile 128x128xBK64; wave 64x64 via 4x4 mfma 16x16x32.
// =========================================================================
template<int MODE, bool ASPLIT, bool SPLITK>
__global__ __launch_bounds__(256, 3) void gemm_bt(
    const void* __restrict__ Ap, const ushort_t* __restrict__ Bm,
    const float* __restrict__ bias,
    float* __restrict__ CoutF, float* __restrict__ CoutF2,
    ushort_t* __restrict__ CoutB,
    int M, int N, int K, long aBatch, long bBatch, long cBatch)
{
  __shared__ __align__(16) ushort_t As[128 * 64];
  __shared__ __align__(16) ushort_t Bs[128 * 64];

  const int tid  = threadIdx.x;
  const int wid  = tid >> 6;
  const int lane = tid & 63;
  const int quad = lane >> 4;
  const int l16  = lane & 15;
  const int m0 = blockIdx.y * 128;
  const int n0 = blockIdx.x * 128;
  const int z  = SPLITK ? (blockIdx.z >> 1) : blockIdx.z;
  const int kh = SPLITK ? (blockIdx.z & 1) : 0;
  const int kbeg = SPLITK ? kh * (K >> 1) : 0;
  const int kend = SPLITK ? kbeg + (K >> 1) : K;
  float* outF = (SPLITK && kh) ? CoutF2 : CoutF;

  const ushort_t* Ab = (const ushort_t*)Ap + (long)z * aBatch;
  const float*    Af = (const float*)Ap + (long)z * aBatch;
  Bm += (long)z * bBatch;

  const int wr = (wid >> 1) * 64;
  const int wc = (wid & 1) * 64;

  // bf16 staging: chunk c = p*256+tid covers row p*32+(tid>>3), sub (tid&7)*8
  const int srow = tid >> 3, ssub = (tid & 7) * 8;
  const long abase = (long)(m0 + srow) * K + ssub;
  const long bbase = (long)(n0 + srow) * K + ssub;

  floatx4 acc[4][4];
#pragma unroll
  for (int i = 0; i < 4; ++i)
#pragma unroll
    for (int j = 0; j < 4; ++j) acc[i][j] = (floatx4){0.f, 0.f, 0.f, 0.f};

  for (int k0 = kbeg; k0 < kend; k0 += 64) {
    __syncthreads();
    if constexpr (ASPLIT) {
#pragma unroll
      for (int p = 0; p < 4; ++p)
        glds16(Ab + abase + 32 * p * (long)K + k0, &As[tid * 8 + p * 2048]);
    } else {
#pragma unroll
      for (int p = 0; p < 8; ++p) {
        int c = tid + p * 256;
        int row = c >> 4, sub = (c & 15) * 4;
        floatx4 va = *(const floatx4*)(Af + (long)(m0 + row) * K + k0 + sub);
        ushortx4 ah;
#pragma unroll
        for (int r = 0; r < 4; ++r) ah[r] = f2b(va[r]);
        *(ushortx4*)(&As[row * 64 + sub]) = ah;
      }
    }
#pragma unroll
    for (int p = 0; p < 4; ++p)
      glds16(Bm + bbase + 32 * p * (long)K + k0, &Bs[tid * 8 + p * 2048]);
    __syncthreads();

#pragma unroll
    for (int kk = 0; kk < 2; ++kk) {
      bf16x8 a[4], b[4];
#pragma unroll
      for (int i = 0; i < 4; ++i)
        a[i] = *(const bf16x8*)(&As[(wr + i * 16 + l16) * 64 + kk * 32 + quad * 8]);
#pragma unroll
      for (int j = 0; j < 4; ++j)
        b[j] = *(const bf16x8*)(&Bs[(wc + j * 16 + l16) * 64 + kk * 32 + quad * 8]);
#pragma unroll
      for (int i = 0; i < 4; ++i)
#pragma unroll
        for (int j = 0; j < 4; ++j)
          acc[i][j] = __builtin_amdgcn_mfma_f32_16x16x32_bf16(a[i], b[j], acc[i][j], 0, 0, 0);
    }
  }

  // epilogue: lane = col l16; rows quad*4+r in each 16x16 sub-tile
#pragma unroll
  for (int j = 0; j < 4; ++j) {
    int col = n0 + wc + j * 16 + l16;
    float bv = (bias != nullptr) ? bias[col] : 0.f;
#pragma unroll
    for (int i = 0; i < 4; ++i) {
      int mbase = m0 + wr + i * 16 + quad * 4;
      if constexpr (MODE == 0) {
#pragma unroll
        for (int r = 0; r < 4; ++r)
          outF[(long)z * cBatch + (long)(mbase + r) * N + col] = acc[i][j][r] + bv;
      } else if constexpr (MODE == 1) {
#pragma unroll
        for (int r = 0; r < 4; ++r)
          CoutB[(long)z * cBatch + (long)(mbase + r) * N + col] = f2b(acc[i][j][r] + bv);
      } else {
        int b = mbase >> 10, jrow = mbase & 1023;
        ushortx4 pk;
#pragma unroll
        for (int r = 0; r < 4; ++r) pk[r] = f2b(acc[i][j][r] + bv);
        *(ushortx4*)(CoutB + ((long)b * N + col) * 1024 + jrow) = pk;
      }
    }
  }
}

// =========================================================================
// convert fp32 -> bf16. 8 elems/thread.
// =========================================================================
__global__ __launch_bounds__(256) void split_kernel(
    const float* __restrict__ src, ushort_t* __restrict__ dst, long nvec)
{
  long i = (long)blockIdx.x * 256 + threadIdx.x;
  if (i >= nvec) return;
  floatx4 a = ((const floatx4*)src)[2 * i];
  floatx4 b = ((const floatx4*)src)[2 * i + 1];
  ushortx4 ha, hb;
#pragma unroll
  for (int r = 0; r < 4; ++r) { ha[r] = f2b(a[r]); hb[r] = f2b(b[r]); }
  ((ushortx4*)dst)[2 * i] = ha; ((ushortx4*)dst)[2 * i + 1] = hb;
}

// =========================================================================
// transpose + convert: T[l][k][j] = bf16(W[l][j][k]), 512x512 per l.
// =========================================================================
__global__ __launch_bounds__(256) void transpose_split_kernel(
    const float* __restrict__ W, ushort_t* __restrict__ T)
{
  __shared__ float tile[64][65];
  const int k0 = blockIdx.x * 64, j0 = blockIdx.y * 64;
  const long base = (long)blockIdx.z * 262144;
  const int tid = threadIdx.x;
#pragma unroll
  for (int p = 0; p < 16; ++p) {
    int idx = tid + p * 256;
    int jj = idx >> 6, kk = idx & 63;
    tile[jj][kk] = W[base + (long)(j0 + jj) * 512 + k0 + kk];
  }
  __syncthreads();
#pragma unroll
  for (int p = 0; p < 16; ++p) {
    int idx = tid + p * 256;
    int kk = idx >> 6, jj = idx & 63;
    T[base + (long)(k0 + kk) * 512 + j0 + jj] = f2b(tile[jj][kk]);
  }
}

// bfused[l][o] = dot(Wconv[l][o][:], bout[l][:]) + bconv[l][o].  wave/output.
__global__ __launch_bounds__(256) void bfuse_kernel(
    const float* __restrict__ Wconv, const float* __restrict__ bout,
    const float* __restrict__ bconv, float* __restrict__ bf)
{
  const int w = threadIdx.x >> 6, lane = threadIdx.x & 63;
  const int gi = blockIdx.x * 4 + w;           // 0..1535
  const int l = gi >> 9, o = gi & 511;
  float p = 0.f;
#pragma unroll
  for (int k = 0; k < 8; ++k)
    p += Wconv[(long)l * 262144 + (long)o * 512 + lane + 64 * k] *
         bout[l * 512 + lane + 64 * k];
#pragma unroll
  for (int msk = 1; msk <= 32; msk <<= 1) p += __shfl_xor(p, msk);
  if (lane == 0) bf[gi] = p + bconv[l * 512 + o];
}

// =========================================================================
// Attention over batch axis: per (n,h), q,k,v are (8 x 64). bf16 in/out.
// =========================================================================
__global__ __launch_bounds__(256) void attn_kernel(
    const ushort_t* __restrict__ qkv, ushort_t* __restrict__ outp)
{
  __shared__ float qs[4][8][65], ks[4][8][65], vs[4][8][65];
  __shared__ float aw[4][64];
  const int w    = threadIdx.x >> 6;
  const int lane = threadIdx.x & 63;
  const int p = blockIdx.x * 4 + w;
  const int n = p >> 3, h = p & 7;

  const long base = (long)n * 1536 + h * 64;
#pragma unroll
  for (int i = 0; i < 8; ++i) {
    long off = base + (long)i * 1024 * 1536;
    qs[w][i][lane] = b2f(qkv[off + lane]);
    ks[w][i][lane] = b2f(qkv[off + 512 + lane]);
    vs[w][i][lane] = b2f(qkv[off + 1024 + lane]);
  }
  __syncthreads();

  const int i = lane >> 3, j = lane & 7;
  float s = 0.f;
#pragma unroll 8
  for (int d = 0; d < 64; ++d) s += qs[w][i][d] * ks[w][j][d];
  s *= 0.125f;

  float m = s;
  m = fmaxf(m, __shfl_xor(m, 1));
  m = fmaxf(m, __shfl_xor(m, 2));
  m = fmaxf(m, __shfl_xor(m, 4));
  float e = __expf(s - m);
  float sum = e;
  sum += __shfl_xor(sum, 1);
  sum += __shfl_xor(sum, 2);
  sum += __shfl_xor(sum, 4);
  aw[w][lane] = e / sum;
  __syncthreads();

  const long ob = (long)n * 512 + h * 64 + lane;
#pragma unroll
  for (int ii = 0; ii < 8; ++ii) {
    float acc = 0.f;
#pragma unroll
    for (int jj = 0; jj < 8; ++jj) acc += aw[w][ii * 8 + jj] * vs[w][jj][lane];
    outp[ob + (long)ii * 1024 * 512] = f2b(acc);
  }
}

// =========================================================================
// x_out = LayerNorm(bf16 x + agg1 + agg2). Wave per row (512).
// =========================================================================
__global__ __launch_bounds__(256) void ln_kernel(
    const ushort_t* __restrict__ xb,
    const float* __restrict__ agg1, const float* __restrict__ agg2,
    float* __restrict__ outF, ushort_t* __restrict__ outB)
{
  const int w = threadIdx.x >> 6, lane = threadIdx.x & 63;
  const long base = ((long)blockIdx.x * 4 + w) * 512;
  float v[8];
  float s = 0.f;
#pragma unroll
  for (int k = 0; k < 8; ++k) {
    long idx = base + lane + 64 * k;
    v[k] = b2f(xb[idx]) + agg1[idx] + agg2[idx];
    s += v[k];
  }
#pragma unroll
  for (int msk = 1; msk <= 32; msk <<= 1) s += __shfl_xor(s, msk);
  float mean = s * (1.f / 512.f);
  float vv = 0.f;
#pragma unroll
  for (int k = 0; k < 8; ++k) { float d = v[k] - mean; vv += d * d; }
#pragma unroll
  for (int msk = 1; msk <= 32; msk <<= 1) vv += __shfl_xor(vv, msk);
  float inv = rsqrtf(vv * (1.f / 512.f) + 1e-5f);
#pragma unroll
  for (int k = 0; k < 8; ++k) {
    long idx = base + lane + 64 * k;
    float val = (v[k] - mean) * inv;
    if (outF) outF[idx] = val;
    else      outB[idx] = f2b(val);
  }
}

// =========================================================================
// Heads: per row of x (8192x512): mastery(1), diff(5), h1, h2. Wave/row.
// =========================================================================
__global__ __launch_bounds__(256) void heads_kernel(
    const float* __restrict__ x,
    const float* __restrict__ Wcls, const float* __restrict__ bcls,
    const float* __restrict__ Wdiff, const float* __restrict__ bdiff,
    const float* __restrict__ Wpre,
    float* __restrict__ mastery, float* __restrict__ diff,
    float* __restrict__ h1, float* __restrict__ h2)
{
  const int w = threadIdx.x >> 6, lane = threadIdx.x & 63;
  const long row = (long)blockIdx.x * 4 + w;
  float xv[8];
#pragma unroll
  for (int k = 0; k < 8; ++k) xv[k] = x[row * 512 + lane + 64 * k];

#pragma unroll
  for (int o = 0; o < 8; ++o) {
    const float* wp = (o == 0) ? Wcls
                    : (o <= 5) ? (Wdiff + (o - 1) * 512)
                    : (o == 6) ? Wpre : (Wpre + 512);
    float p = 0.f;
#pragma unroll
    for (int k = 0; k < 8; ++k) p += xv[k] * wp[lane + 64 * k];
#pragma unroll
    for (int msk = 1; msk <= 32; msk <<= 1) p += __shfl_xor(p, msk);
    if (lane == 0) {
      if (o == 0)      mastery[row] = p + bcls[0];
      else if (o <= 5) diff[row * 5 + (o - 1)] = p + bdiff[o - 1];
      else if (o == 6) h1[row] = p;
      else             h2[row] = p;
    }
  }
}

__global__ __launch_bounds__(256) void prereq_kernel(
    const float* __restrict__ h1, const float* __restrict__ h2,
    const float* __restrict__ bpre, float* __restrict__ outp)
{
  const int b = blockIdx.y, i = blockIdx.x;
  const float base = h1[b * 1024 + i] + bpre[0];
  const long ob = (long)b * (1024 * 1023) + (long)i * 1023;
#pragma unroll
  for (int r = 0; r < 4; ++r) {
    int j = r * 256 + threadIdx.x;
    if (j == i) continue;
    int pos = (j < i) ? j : j - 1;
    outp[ob + pos] = base + h2[b * 1024 + j];
  }
}

__global__ __launch_bounds__(256) void zero_kernel(float* __restrict__ p) {
  p[blockIdx.x * 256 + threadIdx.x] = 0.f;
}

// xm[b,c] += partial sums (grid 256 = 8b x 2cc x 16ns); xm holds SUMS
__global__ __launch_bounds__(256) void pool_kernel(
    const float* __restrict__ x, float* __restrict__ xm)
{
  const int b = blockIdx.x >> 5, cc = (blockIdx.x >> 4) & 1, ns = blockIdx.x & 15;
  const int c = cc * 256 + threadIdx.x;
  float s = 0.f;
  for (int n = ns * 64; n < ns * 64 + 64; ++n)
    s += x[((long)b * 1024 + n) * 512 + c];
  atomicAdd(&xm[b * 512 + c], s);
}

// graph[b,o] = (xm[b]/1024) . Wpool[o] + b_pool[o]
__global__ __launch_bounds__(256) void graph_kernel(
    const float* __restrict__ xm, const float* __restrict__ Wpool,
    const float* __restrict__ bpool, float* __restrict__ g)
{
  const int gi = blockIdx.x * 256 + threadIdx.x;
  const int b = gi >> 9, o = gi & 511;
  float s = 0.f;
  for (int hh = 0; hh < 512; ++hh) s += xm[b * 512 + hh] * Wpool[o * 512 + hh];
  g[gi] = s * (1.f / 1024.f) + bpool[o];
}

// =========================================================================
extern "C" void kernel_launch(void* const* d_in, const int* in_sizes, int n_in,
                              void* d_out, int out_size, void* d_ws, size_t ws_size,
                              hipStream_t stream)
{
  const float* CF    = (const float*)d_in[0];
  const float* ADJ   = (const float*)d_in[1];
  const float* Wemb  = (const float*)d_in[4];
  const float* bemb  = (const float*)d_in[5];
  const float* Win   = (const float*)d_in[6];
  const float* bin   = (const float*)d_in[7];
  const float* Wout  = (const float*)d_in[8];
  const float* bout  = (const float*)d_in[9];
  const float* Wconv = (const float*)d_in[10];
  const float* bconv = (const float*)d_in[11];
  const float* Wcls  = (const float*)d_in[12];
  const float* bcls  = (const float*)d_in[13];
  const float* Wdiff = (const float*)d_in[14];
  const float* bdiff = (const float*)d_in[15];
  const float* Wpre  = (const float*)d_in[16];
  const float* bpre  = (const float*)d_in[17];
  const float* Wpool = (const float*)d_in[18];
  const float* bpool = (const float*)d_in[19];

  // ---- workspace layout (ushort units). Total ~57 MB (< proven 83 MB). ----
  ushort_t* W = (ushort_t*)d_ws;
  ushort_t* xb   = W;                       // 4194304
  ushort_t* qkvb = W + 4194304;             // 12582912 (end 16777216)
  // aliases inside qkv region:
  ushort_t* cT    = qkvb;                   // 4194304 (dead-after-attn reuse)
  ushort_t* WoT   = qkvb + 4194304;         // 786432 (precompute scratch)
  ushort_t* Wembb = qkvb + 4980736;         // 131072
  ushort_t* Wcb   = qkvb + 5111808;         // 786432 (temp Wconv bf16)
  // persistent:
  ushort_t* Winb = W + 16777216;            // 2359296
  ushort_t* Wfb  = W + 19136512;            // 786432 (fused Wconv@Wout)
  ushort_t* ADJb = W + 19922944;            // 8388608 (end 28311552)
  float* bfused = (float*)(W + 28311552);   // 1536
  float* h1     = bfused + 1536;            // 8192
  float* h2     = h1 + 8192;                // 8192
  float* xm     = h2 + 8192;                // 4096

  // ---- output layout (fp32 concat) + d_out-as-scratch aliases ----
  float* out_x       = (float*)d_out;       // 4194304
  float* out_mastery = out_x + 4194304;     // 8192
  float* out_diff    = out_mastery + 8192;  // 40960
  float* out_prereq  = out_diff + 40960;    // 8380416
  float* out_graph   = out_prereq + 8380416;// 4096
  // attn-out bf16 in out_x region (dead until final ln writes it):
  ushort_t* aob = (ushort_t*)out_x;         // 4194304 ushorts = first half
  // split-K partials: agg1 in prereq region, agg2 in out_x region.
  // (aob dead by adjacency time; final ln reads agg2[idx] before writing
  //  out_x[idx] in the same thread — safe.)
  float* agg1 = out_prereq;                 // 4194304 floats
  float* agg2 = out_x;                      // 4194304 floats

  dim3 blk(256);

  // ---- precompute (once per launch) ----
  split_kernel<<<dim3(1152), blk, 0, stream>>>(Win,  Winb,  294912);
  split_kernel<<<dim3(64),   blk, 0, stream>>>(Wemb, Wembb, 16384);
  split_kernel<<<dim3(384),  blk, 0, stream>>>(Wconv, Wcb,  98304);
  split_kernel<<<dim3(4096), blk, 0, stream>>>(ADJ,  ADJb,  1048576);
  transpose_split_kernel<<<dim3(8, 8, 3), blk, 0, stream>>>(Wout, WoT);
  // Wfused[l] = Wconv[l] @ Wout[l]  (batched z=3, 512x512x512)
  gemm_bt<1, true, false><<<dim3(4, 4, 3), blk, 0, stream>>>(
      Wcb, WoT, nullptr, nullptr, nullptr, Wfb,
      512, 512, 512, 262144, 262144, 262144);
  bfuse_kernel<<<dim3(384), blk, 0, stream>>>(Wconv, bout, bconv, bfused);
  zero_kernel<<<dim3(16), blk, 0, stream>>>(xm);

  // x0 = CF @ Wemb^T + bemb  (8192 x 512 x 256, A fp32)
  gemm_bt<1, false, false><<<dim3(4, 64, 1), blk, 0, stream>>>(
      CF, Wembb, bemb, nullptr, nullptr, xb, 8192, 512, 256, 0, 0, 0);

  for (int l = 0; l < 3; ++l) {
    // qkv = x @ Win[l]^T + bin[l]   (8192 x 1536 x 512)
    gemm_bt<1, true, false><<<dim3(12, 64, 1), blk, 0, stream>>>(
        xb, Winb + (long)l * 786432, bin + l * 1536,
        nullptr, nullptr, qkvb, 8192, 1536, 512, 0, 0, 0);
    // attention over batch axis -> aob (out_x scratch)
    attn_kernel<<<dim3(2048), blk, 0, stream>>>(qkvb, aob);
    // convT = (ao @ Wfused[l]^T + bfused[l]) transposed (qkv region dead)
    gemm_bt<2, true, false><<<dim3(4, 64, 1), blk, 0, stream>>>(
        aob, Wfb + (long)l * 262144, bfused + l * 512,
        nullptr, nullptr, cT, 8192, 512, 512, 0, 0, 0);
    // agg[b] = adj[b] @ conv[b]  (batched 1024x512x1024, split-K=2)
    gemm_bt<0, true, true><<<dim3(4, 8, 16), blk, 0, stream>>>(
        ADJb, cT, nullptr, agg1, agg2, nullptr,
        1024, 512, 1024, 1048576, 524288, 524288);
    // x = LN(x + agg1 + agg2)
    if (l < 2)
      ln_kernel<<<dim3(2048), blk, 0, stream>>>(xb, agg1, agg2, nullptr, xb);
    else
      ln_kernel<<<dim3(2048), blk, 0, stream>>>(xb, agg1, agg2, out_x, nullptr);
  }

  heads_kernel<<<dim3(2048), blk, 0, stream>>>(out_x, Wcls, bcls, Wdiff, bdiff,
                                               Wpre, out_mastery, out_diff, h1, h2);
  prereq_kernel<<<dim3(1024, 8), blk, 0, stream>>>(h1, h2, bpre, out_prereq);
  pool_kernel<<<dim3(256), blk, 0, stream>>>(out_x, xm);
  graph_kernel<<<dim3(16), blk, 0, stream>>>(xm, Wpool, bpool, out_graph);
}

// Round 6
// 462.191 us; speedup vs baseline: 2.0363x; 1.0557x over previous
//
#include <hip/hip_runtime.h>
#include <hip/hip_bf16.h>

typedef unsigned short ushort_t;
typedef __attribute__((ext_vector_type(4))) float floatx4;
typedef __attribute__((ext_vector_type(8))) __bf16 bf16x8;
typedef __attribute__((ext_vector_type(4))) unsigned short ushortx4;

// ---------- bf16 helpers ----------
static __device__ __forceinline__ float b2f(ushort_t u) {
  union { unsigned int i; float f; } v; v.i = ((unsigned int)u) << 16; return v.f;
}
static __device__ __forceinline__ ushort_t f2b(float f) {
  unsigned int x = __float_as_uint(f);
  unsigned int r = (x + 0x7fffu + ((x >> 16) & 1u)) >> 16;
  return (ushort_t)r;
}
// async global->LDS, 16B per lane (dest = wave-uniform base + lane*16)
static __device__ __forceinline__ void glds16(const ushort_t* g, ushort_t* l) {
  __builtin_amdgcn_global_load_lds(
      (const __attribute__((address_space(1))) unsigned int*)g,
      (__attribute__((address_space(3))) unsigned int*)l, 16, 0, 0);
}

// =========================================================================
// GEMM: C[M,N] = A[M,K] @ B[N,K]^T (+bias[col]).  Single-plane bf16 MFMA.
// B bf16 k-contig, staged via global_load_lds.
// ASPLIT: A bf16 (glds16) vs fp32 (in-kernel convert).
// SPLITK: gridDim.z = 2*z; blockIdx.z&1 selects K/2 slice; half 0 writes
//         CoutF/CoutB, half 1 writes CoutF2/CoutB2.
// MODE 0: fp32 row-major (+z*cBatch)
// MODE 1: bf16 row-major (+z*cBatch)
// MODE 2: bf16 TRANSPOSED batched: [(b*N+col)*1024 + (m&1023)], b=m>>10
// Block 256 = 4 waves; tile 128x128xBK64; wave 64x64 via 4x4 mfma 16x16x32.
// =========================================================================
template<int MODE, bool ASPLIT, bool SPLITK>
__global__ __launch_bounds__(256, 3) void gemm_bt(
    const void* __restrict__ Ap, const ushort_t* __restrict__ Bm,
    const float* __restrict__ bias,
    float* __restrict__ CoutF, float* __restrict__ CoutF2,
    ushort_t* __restrict__ CoutB, ushort_t* __restrict__ CoutB2,
    int M, int N, int K, long aBatch, long bBatch, long cBatch)
{
  __shared__ __align__(16) ushort_t As[128 * 64];
  __shared__ __align__(16) ushort_t Bs[128 * 64];

  const int tid  = threadIdx.x;
  const int wid  = tid >> 6;
  const int lane = tid & 63;
  const int quad = lane >> 4;
  const int l16  = lane & 15;
  const int m0 = blockIdx.y * 128;
  const int n0 = blockIdx.x * 128;
  const int z  = SPLITK ? (blockIdx.z >> 1) : blockIdx.z;
  const int kh = SPLITK ? (blockIdx.z & 1) : 0;
  const int kbeg = SPLITK ? kh * (K >> 1) : 0;
  const int kend = SPLITK ? kbeg + (K >> 1) : K;
  float*    outF = (SPLITK && kh) ? CoutF2 : CoutF;
  ushort_t* outB = (SPLITK && kh) ? CoutB2 : CoutB;

  const ushort_t* Ab = (const ushort_t*)Ap + (long)z * aBatch;
  const float*    Af = (const float*)Ap + (long)z * aBatch;
  Bm += (long)z * bBatch;

  const int wr = (wid >> 1) * 64;
  const int wc = (wid & 1) * 64;

  const int srow = tid >> 3, ssub = (tid & 7) * 8;
  const long abase = (long)(m0 + srow) * K + ssub;
  const long bbase = (long)(n0 + srow) * K + ssub;

  floatx4 acc[4][4];
#pragma unroll
  for (int i = 0; i < 4; ++i)
#pragma unroll
    for (int j = 0; j < 4; ++j) acc[i][j] = (floatx4){0.f, 0.f, 0.f, 0.f};

  for (int k0 = kbeg; k0 < kend; k0 += 64) {
    __syncthreads();
    if constexpr (ASPLIT) {
#pragma unroll
      for (int p = 0; p < 4; ++p)
        glds16(Ab + abase + 32 * p * (long)K + k0, &As[tid * 8 + p * 2048]);
    } else {
#pragma unroll
      for (int p = 0; p < 8; ++p) {
        int c = tid + p * 256;
        int row = c >> 4, sub = (c & 15) * 4;
        floatx4 va = *(const floatx4*)(Af + (long)(m0 + row) * K + k0 + sub);
        ushortx4 ah;
#pragma unroll
        for (int r = 0; r < 4; ++r) ah[r] = f2b(va[r]);
        *(ushortx4*)(&As[row * 64 + sub]) = ah;
      }
    }
#pragma unroll
    for (int p = 0; p < 4; ++p)
      glds16(Bm + bbase + 32 * p * (long)K + k0, &Bs[tid * 8 + p * 2048]);
    __syncthreads();

#pragma unroll
    for (int kk = 0; kk < 2; ++kk) {
      bf16x8 a[4], b[4];
#pragma unroll
      for (int i = 0; i < 4; ++i)
        a[i] = *(const bf16x8*)(&As[(wr + i * 16 + l16) * 64 + kk * 32 + quad * 8]);
#pragma unroll
      for (int j = 0; j < 4; ++j)
        b[j] = *(const bf16x8*)(&Bs[(wc + j * 16 + l16) * 64 + kk * 32 + quad * 8]);
#pragma unroll
      for (int i = 0; i < 4; ++i)
#pragma unroll
        for (int j = 0; j < 4; ++j)
          acc[i][j] = __builtin_amdgcn_mfma_f32_16x16x32_bf16(a[i], b[j], acc[i][j], 0, 0, 0);
    }
  }

  // epilogue: lane = col l16; rows quad*4+r in each 16x16 sub-tile
#pragma unroll
  for (int j = 0; j < 4; ++j) {
    int col = n0 + wc + j * 16 + l16;
    float bv = (bias != nullptr) ? bias[col] : 0.f;
#pragma unroll
    for (int i = 0; i < 4; ++i) {
      int mbase = m0 + wr + i * 16 + quad * 4;
      if constexpr (MODE == 0) {
#pragma unroll
        for (int r = 0; r < 4; ++r)
          outF[(long)z * cBatch + (long)(mbase + r) * N + col] = acc[i][j][r] + bv;
      } else if constexpr (MODE == 1) {
#pragma unroll
        for (int r = 0; r < 4; ++r)
          outB[(long)z * cBatch + (long)(mbase + r) * N + col] = f2b(acc[i][j][r] + bv);
      } else {
        int b = mbase >> 10, jrow = mbase & 1023;
        ushortx4 pk;
#pragma unroll
        for (int r = 0; r < 4; ++r) pk[r] = f2b(acc[i][j][r] + bv);
        *(ushortx4*)(CoutB + ((long)b * N + col) * 1024 + jrow) = pk;
      }
    }
  }
}

// =========================================================================
// prep: all fp32->bf16 weight/adj conversions + xm zero, one dispatch.
// blocks [0,1152) Win | [1152,1216) Wemb | [1216,1600) Wconv |
// [1600,5696) ADJ | [5696,5712) zero xm.   8 elems/thread.
// =========================================================================
__global__ __launch_bounds__(256) void prep_kernel(
    const float* __restrict__ Win,  ushort_t* __restrict__ Winb,
    const float* __restrict__ Wemb, ushort_t* __restrict__ Wembb,
    const float* __restrict__ Wconv, ushort_t* __restrict__ Wcb,
    const float* __restrict__ ADJ,  ushort_t* __restrict__ ADJb,
    float* __restrict__ xm)
{
  const int bid = blockIdx.x, tid = threadIdx.x;
  const float* src; ushort_t* dst; long i;
  if (bid < 1152)      { src = Win;   dst = Winb;  i = (long)bid * 256 + tid; }
  else if (bid < 1216) { src = Wemb;  dst = Wembb; i = (long)(bid - 1152) * 256 + tid; }
  else if (bid < 1600) { src = Wconv; dst = Wcb;   i = (long)(bid - 1216) * 256 + tid; }
  else if (bid < 5696) { src = ADJ;   dst = ADJb;  i = (long)(bid - 1600) * 256 + tid; }
  else { xm[(bid - 5696) * 256 + tid] = 0.f; return; }
  floatx4 a = ((const floatx4*)src)[2 * i];
  floatx4 b = ((const floatx4*)src)[2 * i + 1];
  ushortx4 ha, hb;
#pragma unroll
  for (int r = 0; r < 4; ++r) { ha[r] = f2b(a[r]); hb[r] = f2b(b[r]); }
  ((ushortx4*)dst)[2 * i] = ha; ((ushortx4*)dst)[2 * i + 1] = hb;
}

// =========================================================================
// transpose + convert: T[l][k][j] = bf16(W[l][j][k]), 512x512 per l.
// =========================================================================
__global__ __launch_bounds__(256) void transpose_split_kernel(
    const float* __restrict__ W, ushort_t* __restrict__ T)
{
  __shared__ float tile[64][65];
  const int k0 = blockIdx.x * 64, j0 = blockIdx.y * 64;
  const long base = (long)blockIdx.z * 262144;
  const int tid = threadIdx.x;
#pragma unroll
  for (int p = 0; p < 16; ++p) {
    int idx = tid + p * 256;
    int jj = idx >> 6, kk = idx & 63;
    tile[jj][kk] = W[base + (long)(j0 + jj) * 512 + k0 + kk];
  }
  __syncthreads();
#pragma unroll
  for (int p = 0; p < 16; ++p) {
    int idx = tid + p * 256;
    int kk = idx >> 6, jj = idx & 63;
    T[base + (long)(k0 + kk) * 512 + j0 + jj] = f2b(tile[jj][kk]);
  }
}

// bfused[l][o] = dot(Wconv[l][o][:], bout[l][:]) + bconv[l][o].  wave/output.
__global__ __launch_bounds__(256) void bfuse_kernel(
    const float* __restrict__ Wconv, const float* __restrict__ bout,
    const float* __restrict__ bconv, float* __restrict__ bf)
{
  const int w = threadIdx.x >> 6, lane = threadIdx.x & 63;
  const int gi = blockIdx.x * 4 + w;           // 0..1535
  const int l = gi >> 9, o = gi & 511;
  float p = 0.f;
#pragma unroll
  for (int k = 0; k < 8; ++k)
    p += Wconv[(long)l * 262144 + (long)o * 512 + lane + 64 * k] *
         bout[l * 512 + lane + 64 * k];
#pragma unroll
  for (int msk = 1; msk <= 32; msk <<= 1) p += __shfl_xor(p, msk);
  if (lane == 0) bf[gi] = p + bconv[l * 512 + o];
}

// =========================================================================
// Attention over batch axis: per (n,h), q,k,v are (8 x 64). bf16 in/out.
// =========================================================================
__global__ __launch_bounds__(256) void attn_kernel(
    const ushort_t* __restrict__ qkv, ushort_t* __restrict__ outp)
{
  __shared__ float qs[4][8][65], ks[4][8][65], vs[4][8][65];
  __shared__ float aw[4][64];
  const int w    = threadIdx.x >> 6;
  const int lane = threadIdx.x & 63;
  const int p = blockIdx.x * 4 + w;
  const int n = p >> 3, h = p & 7;

  const long base = (long)n * 1536 + h * 64;
#pragma unroll
  for (int i = 0; i < 8; ++i) {
    long off = base + (long)i * 1024 * 1536;
    qs[w][i][lane] = b2f(qkv[off + lane]);
    ks[w][i][lane] = b2f(qkv[off + 512 + lane]);
    vs[w][i][lane] = b2f(qkv[off + 1024 + lane]);
  }
  __syncthreads();

  const int i = lane >> 3, j = lane & 7;
  float s = 0.f;
#pragma unroll 8
  for (int d = 0; d < 64; ++d) s += qs[w][i][d] * ks[w][j][d];
  s *= 0.125f;

  float m = s;
  m = fmaxf(m, __shfl_xor(m, 1));
  m = fmaxf(m, __shfl_xor(m, 2));
  m = fmaxf(m, __shfl_xor(m, 4));
  float e = __expf(s - m);
  float sum = e;
  sum += __shfl_xor(sum, 1);
  sum += __shfl_xor(sum, 2);
  sum += __shfl_xor(sum, 4);
  aw[w][lane] = e / sum;
  __syncthreads();

  const long ob = (long)n * 512 + h * 64 + lane;
#pragma unroll
  for (int ii = 0; ii < 8; ++ii) {
    float acc = 0.f;
#pragma unroll
    for (int jj = 0; jj < 8; ++jj) acc += aw[w][ii * 8 + jj] * vs[w][jj][lane];
    outp[ob + (long)ii * 1024 * 512] = f2b(acc);
  }
}

// =========================================================================
// x_out(bf16) = LayerNorm(bf16 x + bf16 aggA + bf16 aggB). Wave per row.
// =========================================================================
__global__ __launch_bounds__(256) void ln_kernel(
    const ushort_t* __restrict__ xb,
    const ushort_t* __restrict__ aggA, const ushort_t* __restrict__ aggB,
    ushort_t* __restrict__ outB)
{
  const int w = threadIdx.x >> 6, lane = threadIdx.x & 63;
  const long base = ((long)blockIdx.x * 4 + w) * 512;
  float v[8];
  float s = 0.f;
#pragma unroll
  for (int k = 0; k < 8; ++k) {
    long idx = base + lane + 64 * k;
    v[k] = b2f(xb[idx]) + b2f(aggA[idx]) + b2f(aggB[idx]);
    s += v[k];
  }
#pragma unroll
  for (int msk = 1; msk <= 32; msk <<= 1) s += __shfl_xor(s, msk);
  float mean = s * (1.f / 512.f);
  float vv = 0.f;
#pragma unroll
  for (int k = 0; k < 8; ++k) { float d = v[k] - mean; vv += d * d; }
#pragma unroll
  for (int msk = 1; msk <= 32; msk <<= 1) vv += __shfl_xor(vv, msk);
  float inv = rsqrtf(vv * (1.f / 512.f) + 1e-5f);
#pragma unroll
  for (int k = 0; k < 8; ++k)
    outB[base + lane + 64 * k] = f2b((v[base >= 0 ? k : k] - mean) * inv);
}

// =========================================================================
// Final layer: LN -> out_x (fp32) + fused heads (mastery, diff, h1, h2).
// Wave per row; the wave already holds the full 512-row in registers.
// =========================================================================
__global__ __launch_bounds__(256) void final_ln_heads_kernel(
    const ushort_t* __restrict__ xb,
    const ushort_t* __restrict__ aggA, const ushort_t* __restrict__ aggB,
    float* __restrict__ out_x,
    const float* __restrict__ Wcls, const float* __restrict__ bcls,
    const float* __restrict__ Wdiff, const float* __restrict__ bdiff,
    const float* __restrict__ Wpre,
    float* __restrict__ mastery, float* __restrict__ diff,
    float* __restrict__ h1, float* __restrict__ h2)
{
  const int w = threadIdx.x >> 6, lane = threadIdx.x & 63;
  const long row = (long)blockIdx.x * 4 + w;
  const long base = row * 512;
  float v[8];
  float s = 0.f;
#pragma unroll
  for (int k = 0; k < 8; ++k) {
    long idx = base + lane + 64 * k;
    v[k] = b2f(xb[idx]) + b2f(aggA[idx]) + b2f(aggB[idx]);
    s += v[k];
  }
#pragma unroll
  for (int msk = 1; msk <= 32; msk <<= 1) s += __shfl_xor(s, msk);
  float mean = s * (1.f / 512.f);
  float vv = 0.f;
#pragma unroll
  for (int k = 0; k < 8; ++k) { float d = v[k] - mean; vv += d * d; }
#pragma unroll
  for (int msk = 1; msk <= 32; msk <<= 1) vv += __shfl_xor(vv, msk);
  float inv = rsqrtf(vv * (1.f / 512.f) + 1e-5f);
#pragma unroll
  for (int k = 0; k < 8; ++k) {
    v[k] = (v[k] - mean) * inv;
    out_x[base + lane + 64 * k] = v[k];
  }
  // fused heads: 8 dot products against the row held in v[]
#pragma unroll
  for (int o = 0; o < 8; ++o) {
    const float* wp = (o == 0) ? Wcls
                    : (o <= 5) ? (Wdiff + (o - 1) * 512)
                    : (o == 6) ? Wpre : (Wpre + 512);
    float p = 0.f;
#pragma unroll
    for (int k = 0; k < 8; ++k) p += v[k] * wp[lane + 64 * k];
#pragma unroll
    for (int msk = 1; msk <= 32; msk <<= 1) p += __shfl_xor(p, msk);
    if (lane == 0) {
      if (o == 0)      mastery[row] = p + bcls[0];
      else if (o <= 5) diff[row * 5 + (o - 1)] = p + bdiff[o - 1];
      else if (o == 6) h1[row] = p;
      else             h2[row] = p;
    }
  }
}

__global__ __launch_bounds__(256) void prereq_kernel(
    const float* __restrict__ h1, const float* __restrict__ h2,
    const float* __restrict__ bpre, float* __restrict__ outp)
{
  const int b = blockIdx.y, i = blockIdx.x;
  const float base = h1[b * 1024 + i] + bpre[0];
  const long ob = (long)b * (1024 * 1023) + (long)i * 1023;
#pragma unroll
  for (int r = 0; r < 4; ++r) {
    int j = r * 256 + threadIdx.x;
    if (j == i) continue;
    int pos = (j < i) ? j : j - 1;
    outp[ob + pos] = base + h2[b * 1024 + j];
  }
}

// xm[b,c] += partial sums (grid 256 = 8b x 2cc x 16ns); xm holds SUMS
__global__ __launch_bounds__(256) void pool_kernel(
    const float* __restrict__ x, float* __restrict__ xm)
{
  const int b = blockIdx.x >> 5, cc = (blockIdx.x >> 4) & 1, ns = blockIdx.x & 15;
  const int c = cc * 256 + threadIdx.x;
  float s = 0.f;
  for (int n = ns * 64; n < ns * 64 + 64; ++n)
    s += x[((long)b * 1024 + n) * 512 + c];
  atomicAdd(&xm[b * 512 + c], s);
}

// graph[b,o] = (xm[b]/1024) . Wpool[o] + b_pool[o]
__global__ __launch_bounds__(256) void graph_kernel(
    const float* __restrict__ xm, const float* __restrict__ Wpool,
    const float* __restrict__ bpool, float* __restrict__ g)
{
  const int gi = blockIdx.x * 256 + threadIdx.x;
  const int b = gi >> 9, o = gi & 511;
  float s = 0.f;
  for (int hh = 0; hh < 512; ++hh) s += xm[b * 512 + hh] * Wpool[o * 512 + hh];
  g[gi] = s * (1.f / 1024.f) + bpool[o];
}

// =========================================================================
extern "C" void kernel_launch(void* const* d_in, const int* in_sizes, int n_in,
                              void* d_out, int out_size, void* d_ws, size_t ws_size,
                              hipStream_t stream)
{
  const float* CF    = (const float*)d_in[0];
  const float* ADJ   = (const float*)d_in[1];
  const float* Wemb  = (const float*)d_in[4];
  const float* bemb  = (const float*)d_in[5];
  const float* Win   = (const float*)d_in[6];
  const float* bin   = (const float*)d_in[7];
  const float* Wout  = (const float*)d_in[8];
  const float* bout  = (const float*)d_in[9];
  const float* Wconv = (const float*)d_in[10];
  const float* bconv = (const float*)d_in[11];
  const float* Wcls  = (const float*)d_in[12];
  const float* bcls  = (const float*)d_in[13];
  const float* Wdiff = (const float*)d_in[14];
  const float* bdiff = (const float*)d_in[15];
  const float* Wpre  = (const float*)d_in[16];
  const float* bpre  = (const float*)d_in[17];
  const float* Wpool = (const float*)d_in[18];
  const float* bpool = (const float*)d_in[19];

  // ---- workspace layout (ushort units). Total ~57 MB (< proven 83 MB). ----
  ushort_t* W = (ushort_t*)d_ws;
  ushort_t* xb   = W;                       // 4194304
  ushort_t* qkvb = W + 4194304;             // 12582912 (end 16777216)
  // aliases inside the qkv region (all dead when their user runs):
  ushort_t* cT    = qkvb;                   // 4194304 (conv out, post-attn)
  ushort_t* aggA  = qkvb + 4194304;         // 4194304 (split-K half 0, bf16)
  ushort_t* aggB  = qkvb + 8388608;         // 4194304 (split-K half 1, bf16)
  // precompute scratch overlays aggA region (dead after setup GEMMs):
  ushort_t* WoT   = qkvb + 4194304;         // 786432
  ushort_t* Wembb = qkvb + 4980736;         // 131072
  ushort_t* Wcb   = qkvb + 5111808;         // 786432 (end 5898240 < 8388608)
  // persistent:
  ushort_t* Winb = W + 16777216;            // 2359296
  ushort_t* Wfb  = W + 19136512;            // 786432 (fused Wconv@Wout)
  ushort_t* ADJb = W + 19922944;            // 8388608 (end 28311552)
  float* bfused = (float*)(W + 28311552);   // 1536
  float* h1     = bfused + 1536;            // 8192
  float* h2     = h1 + 8192;                // 8192
  float* xm     = h2 + 8192;                // 4096

  // ---- output layout (fp32 concat) + d_out-as-scratch aliases ----
  float* out_x       = (float*)d_out;       // 4194304
  float* out_mastery = out_x + 4194304;     // 8192
  float* out_diff    = out_mastery + 8192;  // 40960
  float* out_prereq  = out_diff + 40960;    // 8380416
  float* out_graph   = out_prereq + 8380416;// 4096
  // attn-out bf16 scratch in out_x region (dead before final LN writes it):
  ushort_t* aob = (ushort_t*)out_x;         // 4194304 ushorts

  dim3 blk(256);

  // ---- precompute (once per launch) ----
  prep_kernel<<<dim3(5712), blk, 0, stream>>>(Win, Winb, Wemb, Wembb,
                                              Wconv, Wcb, ADJ, ADJb, xm);
  transpose_split_kernel<<<dim3(8, 8, 3), blk, 0, stream>>>(Wout, WoT);
  // Wfused[l] = Wconv[l] @ Wout[l]  (batched z=3, 512x512x512)
  gemm_bt<1, true, false><<<dim3(4, 4, 3), blk, 0, stream>>>(
      Wcb, WoT, nullptr, nullptr, nullptr, Wfb, nullptr,
      512, 512, 512, 262144, 262144, 262144);
  bfuse_kernel<<<dim3(384), blk, 0, stream>>>(Wconv, bout, bconv, bfused);

  // x0 = CF @ Wemb^T + bemb  (8192 x 512 x 256, A fp32)
  gemm_bt<1, false, false><<<dim3(4, 64, 1), blk, 0, stream>>>(
      CF, Wembb, bemb, nullptr, nullptr, xb, nullptr, 8192, 512, 256, 0, 0, 0);

  for (int l = 0; l < 3; ++l) {
    // qkv = x @ Win[l]^T + bin[l]   (8192 x 1536 x 512)
    gemm_bt<1, true, false><<<dim3(12, 64, 1), blk, 0, stream>>>(
        xb, Winb + (long)l * 786432, bin + l * 1536,
        nullptr, nullptr, qkvb, nullptr, 8192, 1536, 512, 0, 0, 0);
    // attention over batch axis -> aob (out_x scratch)
    attn_kernel<<<dim3(2048), blk, 0, stream>>>(qkvb, aob);
    // convT = (ao @ Wfused[l]^T + bfused[l]) transposed (qkv region dead)
    gemm_bt<2, true, false><<<dim3(4, 64, 1), blk, 0, stream>>>(
        aob, Wfb + (long)l * 262144, bfused + l * 512,
        nullptr, nullptr, cT, nullptr, 8192, 512, 512, 0, 0, 0);
    // agg[b] = adj[b] @ conv[b]  (batched 1024x512x1024, split-K=2,
    // bf16 partials into aggA/aggB)
    gemm_bt<1, true, true><<<dim3(4, 8, 16), blk, 0, stream>>>(
        ADJb, cT, nullptr, nullptr, nullptr, aggA, aggB,
        1024, 512, 1024, 1048576, 524288, 524288);
    // x = LN(x + aggA + aggB)
    if (l < 2)
      ln_kernel<<<dim3(2048), blk, 0, stream>>>(xb, aggA, aggB, xb);
    else
      final_ln_heads_kernel<<<dim3(2048), blk, 0, stream>>>(
          xb, aggA, aggB, out_x, Wcls, bcls, Wdiff, bdiff, Wpre,
          out_mastery, out_diff, h1, h2);
  }

  prereq_kernel<<<dim3(1024, 8), blk, 0, stream>>>(h1, h2, bpre, out_prereq);
  pool_kernel<<<dim3(256), blk, 0, stream>>>(out_x, xm);
  graph_kernel<<<dim3(16), blk, 0, stream>>>(xm, Wpool, bpool, out_graph);
}

// Round 7
// 457.950 us; speedup vs baseline: 2.0552x; 1.0093x over previous
//
#include <hip/hip_runtime.h>
#include <hip/hip_bf16.h>

typedef unsigned short ushort_t;
typedef __attribute__((ext_vector_type(4))) float floatx4;
typedef __attribute__((ext_vector_type(8))) __bf16 bf16x8;
typedef __attribute__((ext_vector_type(4))) unsigned short ushortx4;
typedef __attribute__((ext_vector_type(8))) unsigned short ushortx8;

// ---------- bf16 helpers ----------
static __device__ __forceinline__ float b2f(ushort_t u) {
  union { unsigned int i; float f; } v; v.i = ((unsigned int)u) << 16; return v.f;
}
static __device__ __forceinline__ ushort_t f2b(float f) {
  unsigned int x = __float_as_uint(f);
  unsigned int r = (x + 0x7fffu + ((x >> 16) & 1u)) >> 16;
  return (ushort_t)r;
}
// async global->LDS, 16B per lane (dest = wave-uniform base + lane*16)
static __device__ __forceinline__ void glds16(const ushort_t* g, ushort_t* l) {
  __builtin_amdgcn_global_load_lds(
      (const __attribute__((address_space(1))) unsigned int*)g,
      (__attribute__((address_space(3))) unsigned int*)l, 16, 0, 0);
}

// =========================================================================
// GEMM: C[M,N] = A[M,K] @ B[N,K]^T (+bias[col]).  Single-plane bf16 MFMA.
// XCD swizzle: lin = y*gridX+x; mI = lin % gridY, nI = lin / gridY.
// Same-m blocks differ by gridY (multiple of 8) in linear id -> same XCD
// -> A row-tiles fetched into ONE XCD L2 instead of all 8.
// B bf16 k-contig via global_load_lds. ASPLIT: A bf16 vs fp32 (in-kernel cvt).
// SPLITK: gridDim.z=2*z; blockIdx.z&1 selects K/2 slice -> CoutB/CoutB2.
// MODE 0: fp32 row-major  MODE 1: bf16 row-major
// MODE 2: bf16 TRANSPOSED batched: [(b*N+col)*1024 + (m&1023)], b=m>>10
// Block 256 = 4 waves; tile 128x128xBK64; wave 64x64 via 4x4 mfma 16x16x32.
// =========================================================================
template<int MODE, bool ASPLIT, bool SPLITK>
__global__ __launch_bounds__(256, 3) void gemm_bt(
    const void* __restrict__ Ap, const ushort_t* __restrict__ Bm,
    const float* __restrict__ bias,
    float* __restrict__ CoutF, float* __restrict__ CoutF2,
    ushort_t* __restrict__ CoutB, ushort_t* __restrict__ CoutB2,
    int M, int N, int K, long aBatch, long bBatch, long cBatch)
{
  __shared__ __align__(16) ushort_t As[128 * 64];
  __shared__ __align__(16) ushort_t Bs[128 * 64];

  const int tid  = threadIdx.x;
  const int wid  = tid >> 6;
  const int lane = tid & 63;
  const int quad = lane >> 4;
  const int l16  = lane & 15;
  const int lin = blockIdx.y * gridDim.x + blockIdx.x;
  const int m0 = (lin % gridDim.y) * 128;
  const int n0 = (lin / gridDim.y) * 128;
  const int z  = SPLITK ? (blockIdx.z >> 1) : blockIdx.z;
  const int kh = SPLITK ? (blockIdx.z & 1) : 0;
  const int kbeg = SPLITK ? kh * (K >> 1) : 0;
  const int kend = SPLITK ? kbeg + (K >> 1) : K;
  float*    outF = (SPLITK && kh) ? CoutF2 : CoutF;
  ushort_t* outB = (SPLITK && kh) ? CoutB2 : CoutB;

  const ushort_t* Ab = (const ushort_t*)Ap + (long)z * aBatch;
  const float*    Af = (const float*)Ap + (long)z * aBatch;
  Bm += (long)z * bBatch;

  const int wr = (wid >> 1) * 64;
  const int wc = (wid & 1) * 64;

  const int srow = tid >> 3, ssub = (tid & 7) * 8;
  const long abase = (long)(m0 + srow) * K + ssub;
  const long bbase = (long)(n0 + srow) * K + ssub;

  floatx4 acc[4][4];
#pragma unroll
  for (int i = 0; i < 4; ++i)
#pragma unroll
    for (int j = 0; j < 4; ++j) acc[i][j] = (floatx4){0.f, 0.f, 0.f, 0.f};

  for (int k0 = kbeg; k0 < kend; k0 += 64) {
    __syncthreads();
    if constexpr (ASPLIT) {
#pragma unroll
      for (int p = 0; p < 4; ++p)
        glds16(Ab + abase + 32 * p * (long)K + k0, &As[tid * 8 + p * 2048]);
    } else {
#pragma unroll
      for (int p = 0; p < 8; ++p) {
        int c = tid + p * 256;
        int row = c >> 4, sub = (c & 15) * 4;
        floatx4 va = *(const floatx4*)(Af + (long)(m0 + row) * K + k0 + sub);
        ushortx4 ah;
#pragma unroll
        for (int r = 0; r < 4; ++r) ah[r] = f2b(va[r]);
        *(ushortx4*)(&As[row * 64 + sub]) = ah;
      }
    }
#pragma unroll
    for (int p = 0; p < 4; ++p)
      glds16(Bm + bbase + 32 * p * (long)K + k0, &Bs[tid * 8 + p * 2048]);
    __syncthreads();

#pragma unroll
    for (int kk = 0; kk < 2; ++kk) {
      bf16x8 a[4], b[4];
#pragma unroll
      for (int i = 0; i < 4; ++i)
        a[i] = *(const bf16x8*)(&As[(wr + i * 16 + l16) * 64 + kk * 32 + quad * 8]);
#pragma unroll
      for (int j = 0; j < 4; ++j)
        b[j] = *(const bf16x8*)(&Bs[(wc + j * 16 + l16) * 64 + kk * 32 + quad * 8]);
#pragma unroll
      for (int i = 0; i < 4; ++i)
#pragma unroll
        for (int j = 0; j < 4; ++j)
          acc[i][j] = __builtin_amdgcn_mfma_f32_16x16x32_bf16(a[i], b[j], acc[i][j], 0, 0, 0);
    }
  }

  // epilogue: lane = col l16; rows quad*4+r in each 16x16 sub-tile
#pragma unroll
  for (int j = 0; j < 4; ++j) {
    int col = n0 + wc + j * 16 + l16;
    float bv = (bias != nullptr) ? bias[col] : 0.f;
#pragma unroll
    for (int i = 0; i < 4; ++i) {
      int mbase = m0 + wr + i * 16 + quad * 4;
      if constexpr (MODE == 0) {
#pragma unroll
        for (int r = 0; r < 4; ++r)
          outF[(long)z * cBatch + (long)(mbase + r) * N + col] = acc[i][j][r] + bv;
      } else if constexpr (MODE == 1) {
#pragma unroll
        for (int r = 0; r < 4; ++r)
          outB[(long)z * cBatch + (long)(mbase + r) * N + col] = f2b(acc[i][j][r] + bv);
      } else {
        int b = mbase >> 10, jrow = mbase & 1023;
        ushortx4 pk;
#pragma unroll
        for (int r = 0; r < 4; ++r) pk[r] = f2b(acc[i][j][r] + bv);
        *(ushortx4*)(CoutB + ((long)b * N + col) * 1024 + jrow) = pk;
      }
    }
  }
}

// =========================================================================
// prep: all fp32->bf16 weight/adj conversions + xm zero, one dispatch.
// =========================================================================
__global__ __launch_bounds__(256) void prep_kernel(
    const float* __restrict__ Win,  ushort_t* __restrict__ Winb,
    const float* __restrict__ Wemb, ushort_t* __restrict__ Wembb,
    const float* __restrict__ Wconv, ushort_t* __restrict__ Wcb,
    const float* __restrict__ ADJ,  ushort_t* __restrict__ ADJb,
    float* __restrict__ xm)
{
  const int bid = blockIdx.x, tid = threadIdx.x;
  const float* src; ushort_t* dst; long i;
  if (bid < 1152)      { src = Win;   dst = Winb;  i = (long)bid * 256 + tid; }
  else if (bid < 1216) { src = Wemb;  dst = Wembb; i = (long)(bid - 1152) * 256 + tid; }
  else if (bid < 1600) { src = Wconv; dst = Wcb;   i = (long)(bid - 1216) * 256 + tid; }
  else if (bid < 5696) { src = ADJ;   dst = ADJb;  i = (long)(bid - 1600) * 256 + tid; }
  else { xm[(bid - 5696) * 256 + tid] = 0.f; return; }
  floatx4 a = ((const floatx4*)src)[2 * i];
  floatx4 b = ((const floatx4*)src)[2 * i + 1];
  ushortx4 ha, hb;
#pragma unroll
  for (int r = 0; r < 4; ++r) { ha[r] = f2b(a[r]); hb[r] = f2b(b[r]); }
  ((ushortx4*)dst)[2 * i] = ha; ((ushortx4*)dst)[2 * i + 1] = hb;
}

// =========================================================================
// transpose + convert: T[l][k][j] = bf16(W[l][j][k]), 512x512 per l.
// =========================================================================
__global__ __launch_bounds__(256) void transpose_split_kernel(
    const float* __restrict__ W, ushort_t* __restrict__ T)
{
  __shared__ float tile[64][65];
  const int k0 = blockIdx.x * 64, j0 = blockIdx.y * 64;
  const long base = (long)blockIdx.z * 262144;
  const int tid = threadIdx.x;
#pragma unroll
  for (int p = 0; p < 16; ++p) {
    int idx = tid + p * 256;
    int jj = idx >> 6, kk = idx & 63;
    tile[jj][kk] = W[base + (long)(j0 + jj) * 512 + k0 + kk];
  }
  __syncthreads();
#pragma unroll
  for (int p = 0; p < 16; ++p) {
    int idx = tid + p * 256;
    int kk = idx >> 6, jj = idx & 63;
    T[base + (long)(k0 + kk) * 512 + j0 + jj] = f2b(tile[jj][kk]);
  }
}

// bfused[l][o] = dot(Wconv[l][o][:], bout[l][:]) + bconv[l][o].  wave/output.
__global__ __launch_bounds__(256) void bfuse_kernel(
    const float* __restrict__ Wconv, const float* __restrict__ bout,
    const float* __restrict__ bconv, float* __restrict__ bf)
{
  const int w = threadIdx.x >> 6, lane = threadIdx.x & 63;
  const int gi = blockIdx.x * 4 + w;           // 0..1535
  const int l = gi >> 9, o = gi & 511;
  float p = 0.f;
#pragma unroll
  for (int k = 0; k < 8; ++k)
    p += Wconv[(long)l * 262144 + (long)o * 512 + lane + 64 * k] *
         bout[l * 512 + lane + 64 * k];
#pragma unroll
  for (int msk = 1; msk <= 32; msk <<= 1) p += __shfl_xor(p, msk);
  if (lane == 0) bf[gi] = p + bconv[l * 512 + o];
}

// =========================================================================
// Attention over batch axis. Block (512 thr) per node n; cooperative
// coalesced load of q,k,v (8 batches x 1536) into LDS floats (stride 1540
// breaks the 8-way bank alias); wave w = head h computes its 8x8 softmax.
// =========================================================================
__global__ __launch_bounds__(512) void attn_kernel(
    const ushort_t* __restrict__ qkv, ushort_t* __restrict__ outp)
{
  __shared__ float qs[8 * 1540];      // [i][1540], cols 0..511 q, 512 k, 1024 v
  __shared__ float aw[8][64];
  const int tid = threadIdx.x;
  const int n = blockIdx.x;

  // load 8 rows x 1536 ushorts = 1536 chunks of 8; 512 thr -> 3 passes
  const ushort_t* src = qkv + (long)n * 1536;
#pragma unroll
  for (int p = 0; p < 3; ++p) {
    int c = tid + p * 512;
    int i = c / 192, off = (c % 192) * 8;
    ushortx8 u = *(const ushortx8*)(src + (long)i * 1024 * 1536 + off);
    float* d = &qs[i * 1540 + off];
#pragma unroll
    for (int r = 0; r < 8; ++r) d[r] = b2f(u[r]);
  }
  __syncthreads();

  const int h    = tid >> 6;          // wave = head
  const int lane = tid & 63;
  const int i = lane >> 3, j = lane & 7;
  float s = 0.f;
#pragma unroll 8
  for (int d = 0; d < 64; ++d)
    s += qs[i * 1540 + h * 64 + d] * qs[j * 1540 + 512 + h * 64 + d];
  s *= 0.125f;

  float m = s;
  m = fmaxf(m, __shfl_xor(m, 1));
  m = fmaxf(m, __shfl_xor(m, 2));
  m = fmaxf(m, __shfl_xor(m, 4));
  float e = __expf(s - m);
  float sum = e;
  sum += __shfl_xor(sum, 1);
  sum += __shfl_xor(sum, 2);
  sum += __shfl_xor(sum, 4);
  aw[h][lane] = e / sum;              // wave-local; lgkmcnt orders within wave

  // lane = d; o[ii][d] = sum_jj a[ii][jj] * v[jj][d]
  const long ob = (long)n * 512 + h * 64 + lane;
#pragma unroll
  for (int ii = 0; ii < 8; ++ii) {
    float acc = 0.f;
#pragma unroll
    for (int jj = 0; jj < 8; ++jj)
      acc += aw[h][ii * 8 + jj] * qs[jj * 1540 + 1024 + h * 64 + lane];
    outp[ob + (long)ii * 1024 * 512] = f2b(acc);
  }
}

// =========================================================================
// x_out(bf16) = LayerNorm(bf16 x + bf16 aggA + bf16 aggB). Wave per row.
// =========================================================================
__global__ __launch_bounds__(256) void ln_kernel(
    const ushort_t* __restrict__ xb,
    const ushort_t* __restrict__ aggA, const ushort_t* __restrict__ aggB,
    ushort_t* __restrict__ outB)
{
  const int w = threadIdx.x >> 6, lane = threadIdx.x & 63;
  const long base = ((long)blockIdx.x * 4 + w) * 512;
  float v[8];
  float s = 0.f;
#pragma unroll
  for (int k = 0; k < 8; ++k) {
    long idx = base + lane + 64 * k;
    v[k] = b2f(xb[idx]) + b2f(aggA[idx]) + b2f(aggB[idx]);
    s += v[k];
  }
#pragma unroll
  for (int msk = 1; msk <= 32; msk <<= 1) s += __shfl_xor(s, msk);
  float mean = s * (1.f / 512.f);
  float vv = 0.f;
#pragma unroll
  for (int k = 0; k < 8; ++k) { float d = v[k] - mean; vv += d * d; }
#pragma unroll
  for (int msk = 1; msk <= 32; msk <<= 1) vv += __shfl_xor(vv, msk);
  float inv = rsqrtf(vv * (1.f / 512.f) + 1e-5f);
#pragma unroll
  for (int k = 0; k < 8; ++k)
    outB[base + lane + 64 * k] = f2b((v[k] - mean) * inv);
}

// =========================================================================
// Final layer: LN -> out_x (fp32) + fused heads (mastery, diff, h1, h2).
// =========================================================================
__global__ __launch_bounds__(256) void final_ln_heads_kernel(
    const ushort_t* __restrict__ xb,
    const ushort_t* __restrict__ aggA, const ushort_t* __restrict__ aggB,
    float* __restrict__ out_x,
    const float* __restrict__ Wcls, const float* __restrict__ bcls,
    const float* __restrict__ Wdiff, const float* __restrict__ bdiff,
    const float* __restrict__ Wpre,
    float* __restrict__ mastery, float* __restrict__ diff,
    float* __restrict__ h1, float* __restrict__ h2)
{
  const int w = threadIdx.x >> 6, lane = threadIdx.x & 63;
  const long row = (long)blockIdx.x * 4 + w;
  const long base = row * 512;
  float v[8];
  float s = 0.f;
#pragma unroll
  for (int k = 0; k < 8; ++k) {
    long idx = base + lane + 64 * k;
    v[k] = b2f(xb[idx]) + b2f(aggA[idx]) + b2f(aggB[idx]);
    s += v[k];
  }
#pragma unroll
  for (int msk = 1; msk <= 32; msk <<= 1) s += __shfl_xor(s, msk);
  float mean = s * (1.f / 512.f);
  float vv = 0.f;
#pragma unroll
  for (int k = 0; k < 8; ++k) { float d = v[k] - mean; vv += d * d; }
#pragma unroll
  for (int msk = 1; msk <= 32; msk <<= 1) vv += __shfl_xor(vv, msk);
  float inv = rsqrtf(vv * (1.f / 512.f) + 1e-5f);
#pragma unroll
  for (int k = 0; k < 8; ++k) {
    v[k] = (v[k] - mean) * inv;
    out_x[base + lane + 64 * k] = v[k];
  }
#pragma unroll
  for (int o = 0; o < 8; ++o) {
    const float* wp = (o == 0) ? Wcls
                    : (o <= 5) ? (Wdiff + (o - 1) * 512)
                    : (o == 6) ? Wpre : (Wpre + 512);
    float p = 0.f;
#pragma unroll
    for (int k = 0; k < 8; ++k) p += v[k] * wp[lane + 64 * k];
#pragma unroll
    for (int msk = 1; msk <= 32; msk <<= 1) p += __shfl_xor(p, msk);
    if (lane == 0) {
      if (o == 0)      mastery[row] = p + bcls[0];
      else if (o <= 5) diff[row * 5 + (o - 1)] = p + bdiff[o - 1];
      else if (o == 6) h1[row] = p;
      else             h2[row] = p;
    }
  }
}

// =========================================================================
// epilogue fused: [0,8192) prereq rows, [8192,8448) pool partials.
// =========================================================================
__global__ __launch_bounds__(256) void epi_kernel(
    const float* __restrict__ h1, const float* __restrict__ h2,
    const float* __restrict__ bpre, float* __restrict__ outp,
    const float* __restrict__ x, float* __restrict__ xm)
{
  const int bid = blockIdx.x;
  if (bid < 8192) {
    const int b = bid >> 10, i = bid & 1023;
    const float base = h1[b * 1024 + i] + bpre[0];
    const long ob = (long)b * (1024 * 1023) + (long)i * 1023;
#pragma unroll
    for (int r = 0; r < 4; ++r) {
      int j = r * 256 + threadIdx.x;
      if (j == i) continue;
      int pos = (j < i) ? j : j - 1;
      outp[ob + pos] = base + h2[b * 1024 + j];
    }
  } else {
    const int pb = bid - 8192;
    const int b = pb >> 5, cc = (pb >> 4) & 1, ns = pb & 15;
    const int c = cc * 256 + threadIdx.x;
    float s = 0.f;
    for (int n = ns * 64; n < ns * 64 + 64; ++n)
      s += x[((long)b * 1024 + n) * 512 + c];
    atomicAdd(&xm[b * 512 + c], s);
  }
}

// graph[b,o] = (xm[b]/1024) . Wpool[o] + b_pool[o]
__global__ __launch_bounds__(256) void graph_kernel(
    const float* __restrict__ xm, const float* __restrict__ Wpool,
    const float* __restrict__ bpool, float* __restrict__ g)
{
  const int gi = blockIdx.x * 256 + threadIdx.x;
  const int b = gi >> 9, o = gi & 511;
  float s = 0.f;
  for (int hh = 0; hh < 512; ++hh) s += xm[b * 512 + hh] * Wpool[o * 512 + hh];
  g[gi] = s * (1.f / 1024.f) + bpool[o];
}

// =========================================================================
extern "C" void kernel_launch(void* const* d_in, const int* in_sizes, int n_in,
                              void* d_out, int out_size, void* d_ws, size_t ws_size,
                              hipStream_t stream)
{
  const float* CF    = (const float*)d_in[0];
  const float* ADJ   = (const float*)d_in[1];
  const float* Wemb  = (const float*)d_in[4];
  const float* bemb  = (const float*)d_in[5];
  const float* Win   = (const float*)d_in[6];
  const float* bin   = (const float*)d_in[7];
  const float* Wout  = (const float*)d_in[8];
  const float* bout  = (const float*)d_in[9];
  const float* Wconv = (const float*)d_in[10];
  const float* bconv = (const float*)d_in[11];
  const float* Wcls  = (const float*)d_in[12];
  const float* bcls  = (const float*)d_in[13];
  const float* Wdiff = (const float*)d_in[14];
  const float* bdiff = (const float*)d_in[15];
  const float* Wpre  = (const float*)d_in[16];
  const float* bpre  = (const float*)d_in[17];
  const float* Wpool = (const float*)d_in[18];
  const float* bpool = (const float*)d_in[19];

  // ---- workspace layout (ushort units). Total ~57 MB (< proven 83 MB). ----
  ushort_t* W = (ushort_t*)d_ws;
  ushort_t* xb   = W;                       // 4194304
  ushort_t* qkvb = W + 4194304;             // 12582912 (end 16777216)
  // aliases inside the qkv region (all dead when their user runs):
  ushort_t* cT    = qkvb;                   // 4194304 (conv out, post-attn)
  ushort_t* aggA  = qkvb + 4194304;         // 4194304 (split-K half 0, bf16)
  ushort_t* aggB  = qkvb + 8388608;         // 4194304 (split-K half 1, bf16)
  // precompute scratch overlays aggA region (dead after setup GEMMs):
  ushort_t* WoT   = qkvb + 4194304;         // 786432
  ushort_t* Wembb = qkvb + 4980736;         // 131072
  ushort_t* Wcb   = qkvb + 5111808;         // 786432 (end 5898240 < 8388608)
  // persistent:
  ushort_t* Winb = W + 16777216;            // 2359296
  ushort_t* Wfb  = W + 19136512;            // 786432 (fused Wconv@Wout)
  ushort_t* ADJb = W + 19922944;            // 8388608 (end 28311552)
  float* bfused = (float*)(W + 28311552);   // 1536
  float* h1     = bfused + 1536;            // 8192
  float* h2     = h1 + 8192;                // 8192
  float* xm     = h2 + 8192;                // 4096

  // ---- output layout (fp32 concat) + d_out-as-scratch aliases ----
  float* out_x       = (float*)d_out;       // 4194304
  float* out_mastery = out_x + 4194304;     // 8192
  float* out_diff    = out_mastery + 8192;  // 40960
  float* out_prereq  = out_diff + 40960;    // 8380416
  float* out_graph   = out_prereq + 8380416;// 4096
  // attn-out bf16 scratch in out_x region (dead before final LN writes it):
  ushort_t* aob = (ushort_t*)out_x;         // 4194304 ushorts

  dim3 blk(256);

  // ---- precompute (once per launch) ----
  prep_kernel<<<dim3(5712), blk, 0, stream>>>(Win, Winb, Wemb, Wembb,
                                              Wconv, Wcb, ADJ, ADJb, xm);
  transpose_split_kernel<<<dim3(8, 8, 3), blk, 0, stream>>>(Wout, WoT);
  // Wfused[l] = Wconv[l] @ Wout[l]  (batched z=3, 512x512x512)
  gemm_bt<1, true, false><<<dim3(4, 4, 3), blk, 0, stream>>>(
      Wcb, WoT, nullptr, nullptr, nullptr, Wfb, nullptr,
      512, 512, 512, 262144, 262144, 262144);
  bfuse_kernel<<<dim3(384), blk, 0, stream>>>(Wconv, bout, bconv, bfused);

  // x0 = CF @ Wemb^T + bemb  (8192 x 512 x 256, A fp32)
  gemm_bt<1, false, false><<<dim3(4, 64, 1), blk, 0, stream>>>(
      CF, Wembb, bemb, nullptr, nullptr, xb, nullptr, 8192, 512, 256, 0, 0, 0);

  for (int l = 0; l < 3; ++l) {
    // qkv = x @ Win[l]^T + bin[l]   (8192 x 1536 x 512)
    gemm_bt<1, true, false><<<dim3(12, 64, 1), blk, 0, stream>>>(
        xb, Winb + (long)l * 786432, bin + l * 1536,
        nullptr, nullptr, qkvb, nullptr, 8192, 1536, 512, 0, 0, 0);
    // attention over batch axis -> aob (out_x scratch)
    attn_kernel<<<dim3(1024), dim3(512), 0, stream>>>(qkvb, aob);
    // convT = (ao @ Wfused[l]^T + bfused[l]) transposed (qkv region dead)
    gemm_bt<2, true, false><<<dim3(4, 64, 1), blk, 0, stream>>>(
        aob, Wfb + (long)l * 262144, bfused + l * 512,
        nullptr, nullptr, cT, nullptr, 8192, 512, 512, 0, 0, 0);
    // agg[b] = adj[b] @ conv[b]  (batched 1024x512x1024, split-K=2, bf16)
    gemm_bt<1, true, true><<<dim3(4, 8, 16), blk, 0, stream>>>(
        ADJb, cT, nullptr, nullptr, nullptr, aggA, aggB,
        1024, 512, 1024, 1048576, 524288, 524288);
    // x = LN(x + aggA + aggB)
    if (l < 2)
      ln_kernel<<<dim3(2048), blk, 0, stream>>>(xb, aggA, aggB, xb);
    else
      final_ln_heads_kernel<<<dim3(2048), blk, 0, stream>>>(
          xb, aggA, aggB, out_x, Wcls, bcls, Wdiff, bdiff, Wpre,
          out_mastery, out_diff, h1, h2);
  }

  epi_kernel<<<dim3(8448), blk, 0, stream>>>(h1, h2, bpre, out_prereq,
                                             out_x, xm);
  graph_kernel<<<dim3(16), blk, 0, stream>>>(xm, Wpool, bpool, out_graph);
}

// Round 8
// 455.027 us; speedup vs baseline: 2.0683x; 1.0064x over previous
//
#include <hip/hip_runtime.h>
#include <hip/hip_bf16.h>

typedef unsigned short ushort_t;
typedef __attribute__((ext_vector_type(4))) float floatx4;
typedef __attribute__((ext_vector_type(8))) __bf16 bf16x8;
typedef __attribute__((ext_vector_type(4))) unsigned short ushortx4;
typedef __attribute__((ext_vector_type(8))) unsigned short ushortx8;

// ---------- bf16 helpers ----------
static __device__ __forceinline__ float b2f(ushort_t u) {
  union { unsigned int i; float f; } v; v.i = ((unsigned int)u) << 16; return v.f;
}
static __device__ __forceinline__ ushort_t f2b(float f) {
  unsigned int x = __float_as_uint(f);
  unsigned int r = (x + 0x7fffu + ((x >> 16) & 1u)) >> 16;
  return (ushort_t)r;
}
// async global->LDS, 16B per lane (dest = wave-uniform base + lane*16)
static __device__ __forceinline__ void glds16(const ushort_t* g, ushort_t* l) {
  __builtin_amdgcn_global_load_lds(
      (const __attribute__((address_space(1))) unsigned int*)g,
      (__attribute__((address_space(3))) unsigned int*)l, 16, 0, 0);
}

// =========================================================================
// GEMM: C[M,N] = A[M,K] @ B[N,K]^T (+bias[col]).  Single-plane bf16 MFMA.
// LDS bank-conflict fix: k-chunk XOR swizzle. LDS slot (row, c) holds the
// global 16B k-chunk (c ^ (row&7)); rows stay contiguous (glds16-safe) and
// fragment reads (16 rows @ one k-chunk) spread over all 8 slots -> 2
// lanes/bank = conflict-free (was 16-way, ~3M SQ_LDS_BANK_CONFLICT).
// XCD swizzle: lin = y*gridX+x; m = lin%gridY, n = lin/gridY.
// KS: split-K ways (1/2/4); blockIdx.z = z*KS+kq; partial kq -> Cout[kq].
// MODE 1: bf16 row-major (+z*cBatch)
// MODE 2: bf16 TRANSPOSED batched: [(b*N+col)*1024 + (m&1023)], b=m>>10
// Block 256 = 4 waves; tile 128x128xBK64; wave 64x64 via 4x4 mfma 16x16x32.
// =========================================================================
template<int MODE, bool ASPLIT, int KS>
__global__ __launch_bounds__(256, 3) void gemm_bt(
    const void* __restrict__ Ap, const ushort_t* __restrict__ Bm,
    const float* __restrict__ bias,
    ushort_t* __restrict__ C0, ushort_t* __restrict__ C1,
    ushort_t* __restrict__ C2, ushort_t* __restrict__ C3,
    int M, int N, int K, long aBatch, long bBatch, long cBatch)
{
  __shared__ __align__(16) ushort_t As[128 * 64];
  __shared__ __align__(16) ushort_t Bs[128 * 64];

  const int tid  = threadIdx.x;
  const int wid  = tid >> 6;
  const int lane = tid & 63;
  const int quad = lane >> 4;
  const int l16  = lane & 15;
  const int lin = blockIdx.y * gridDim.x + blockIdx.x;
  const int m0 = (lin % gridDim.y) * 128;
  const int n0 = (lin / gridDim.y) * 128;
  const int z  = (KS > 1) ? (int)(blockIdx.z / KS) : blockIdx.z;
  const int kq = (KS > 1) ? (int)(blockIdx.z % KS) : 0;
  const int kbeg = kq * (K / KS);
  const int kend = kbeg + (K / KS);
  ushort_t* outB = C0;
  if (KS >= 2 && kq == 1) outB = C1;
  if (KS >= 4 && kq == 2) outB = C2;
  if (KS >= 4 && kq == 3) outB = C3;

  const ushort_t* Ab = (const ushort_t*)Ap + (long)z * aBatch;
  const float*    Af = (const float*)Ap + (long)z * aBatch;
  Bm += (long)z * bBatch;

  const int wr = (wid >> 1) * 64;
  const int wc = (wid & 1) * 64;

  // staging: thread covers LDS slot (srow, tid&7); global source chunk is
  // XOR-swizzled: scj = (tid&7) ^ (srow&7)
  const int srow = tid >> 3;
  const int scj  = ((tid & 7) ^ (srow & 7)) * 8;
  const long abase = (long)(m0 + srow) * K + scj;
  const long bbase = (long)(n0 + srow) * K + scj;

  floatx4 acc[4][4];
#pragma unroll
  for (int i = 0; i < 4; ++i)
#pragma unroll
    for (int j = 0; j < 4; ++j) acc[i][j] = (floatx4){0.f, 0.f, 0.f, 0.f};

  const int rx = l16 & 7;   // row&7 for all fragment rows (wr,wc,i*16 mult 8)

  for (int k0 = kbeg; k0 < kend; k0 += 64) {
    __syncthreads();
    if constexpr (ASPLIT) {
#pragma unroll
      for (int p = 0; p < 4; ++p)
        glds16(Ab + abase + 32 * p * (long)K + k0, &As[tid * 8 + p * 2048]);
    } else {
#pragma unroll
      for (int p = 0; p < 8; ++p) {
        int c = tid + p * 256;
        int row = c >> 4, sub4 = c & 15;
        floatx4 va = *(const floatx4*)(Af + (long)(m0 + row) * K + k0 + sub4 * 4);
        ushortx4 ah;
#pragma unroll
        for (int r = 0; r < 4; ++r) ah[r] = f2b(va[r]);
        int dst = row * 64 + (((sub4 >> 1) ^ (row & 7)) << 3) + ((sub4 & 1) << 2);
        *(ushortx4*)(&As[dst]) = ah;
      }
    }
#pragma unroll
    for (int p = 0; p < 4; ++p)
      glds16(Bm + bbase + 32 * p * (long)K + k0, &Bs[tid * 8 + p * 2048]);
    __syncthreads();

#pragma unroll
    for (int kk = 0; kk < 2; ++kk) {
      bf16x8 a[4], b[4];
#pragma unroll
      for (int i = 0; i < 4; ++i)
        a[i] = *(const bf16x8*)(&As[(wr + i * 16 + l16) * 64 +
                                    (((kk * 4 + quad) ^ rx) << 3)]);
#pragma unroll
      for (int j = 0; j < 4; ++j)
        b[j] = *(const bf16x8*)(&Bs[(wc + j * 16 + l16) * 64 +
                                    (((kk * 4 + quad) ^ rx) << 3)]);
#pragma unroll
      for (int i = 0; i < 4; ++i)
#pragma unroll
        for (int j = 0; j < 4; ++j)
          acc[i][j] = __builtin_amdgcn_mfma_f32_16x16x32_bf16(a[i], b[j], acc[i][j], 0, 0, 0);
    }
  }

  // epilogue: lane = col l16; rows quad*4+r in each 16x16 sub-tile
#pragma unroll
  for (int j = 0; j < 4; ++j) {
    int col = n0 + wc + j * 16 + l16;
    float bv = (bias != nullptr) ? bias[col] : 0.f;
#pragma unroll
    for (int i = 0; i < 4; ++i) {
      int mbase = m0 + wr + i * 16 + quad * 4;
      if constexpr (MODE == 1) {
#pragma unroll
        for (int r = 0; r < 4; ++r)
          outB[(long)z * cBatch + (long)(mbase + r) * N + col] = f2b(acc[i][j][r] + bv);
      } else {
        int b = mbase >> 10, jrow = mbase & 1023;
        ushortx4 pk;
#pragma unroll
        for (int r = 0; r < 4; ++r) pk[r] = f2b(acc[i][j][r] + bv);
        *(ushortx4*)(outB + ((long)b * N + col) * 1024 + jrow) = pk;
      }
    }
  }
}

// =========================================================================
// prep (one dispatch): fp32->bf16 conversions, xm zero, Wout transpose,
// bfused.  blocks: [0,1152) Win | [1152,1216) Wemb | [1216,1600) Wconv |
// [1600,5696) ADJ | [5696,5712) zero xm | [5712,5904) WoutT | [5904,6288) bfuse
// =========================================================================
__global__ __launch_bounds__(256) void prep_kernel(
    const float* __restrict__ Win,  ushort_t* __restrict__ Winb,
    const float* __restrict__ Wemb, ushort_t* __restrict__ Wembb,
    const float* __restrict__ Wconv, ushort_t* __restrict__ Wcb,
    const float* __restrict__ ADJ,  ushort_t* __restrict__ ADJb,
    float* __restrict__ xm,
    const float* __restrict__ Wout, ushort_t* __restrict__ WoT,
    const float* __restrict__ bout, const float* __restrict__ bconv,
    float* __restrict__ bfused)
{
  __shared__ float tile[64][65];
  const int bid = blockIdx.x, tid = threadIdx.x;
  if (bid < 5696) {
    const float* src; ushort_t* dst; long i;
    if (bid < 1152)      { src = Win;   dst = Winb;  i = (long)bid * 256 + tid; }
    else if (bid < 1216) { src = Wemb;  dst = Wembb; i = (long)(bid - 1152) * 256 + tid; }
    else if (bid < 1600) { src = Wconv; dst = Wcb;   i = (long)(bid - 1216) * 256 + tid; }
    else                 { src = ADJ;   dst = ADJb;  i = (long)(bid - 1600) * 256 + tid; }
    floatx4 a = ((const floatx4*)src)[2 * i];
    floatx4 b = ((const floatx4*)src)[2 * i + 1];
    ushortx4 ha, hb;
#pragma unroll
    for (int r = 0; r < 4; ++r) { ha[r] = f2b(a[r]); hb[r] = f2b(b[r]); }
    ((ushortx4*)dst)[2 * i] = ha; ((ushortx4*)dst)[2 * i + 1] = hb;
  } else if (bid < 5712) {
    xm[(bid - 5696) * 256 + tid] = 0.f;
  } else if (bid < 5904) {
    // transpose+cvt: T[l][k][j] = bf16(Wout[l][j][k])
    const int t = bid - 5712;
    const int z = t >> 6, k0 = ((t >> 3) & 7) * 64, j0 = (t & 7) * 64;
    const long base = (long)z * 262144;
#pragma unroll
    for (int p = 0; p < 16; ++p) {
      int idx = tid + p * 256;
      int jj = idx >> 6, kk = idx & 63;
      tile[jj][kk] = Wout[base + (long)(j0 + jj) * 512 + k0 + kk];
    }
    __syncthreads();
#pragma unroll
    for (int p = 0; p < 16; ++p) {
      int idx = tid + p * 256;
      int kk = idx >> 6, jj = idx & 63;
      WoT[base + (long)(k0 + kk) * 512 + j0 + jj] = f2b(tile[jj][kk]);
    }
  } else {
    // bfused[l][o] = dot(Wconv[l][o][:], bout[l][:]) + bconv[l][o]
    const int w = tid >> 6, lane = tid & 63;
    const int gi = (bid - 5904) * 4 + w;
    const int l = gi >> 9, o = gi & 511;
    float p = 0.f;
#pragma unroll
    for (int k = 0; k < 8; ++k)
      p += Wconv[(long)l * 262144 + (long)o * 512 + lane + 64 * k] *
           bout[l * 512 + lane + 64 * k];
#pragma unroll
    for (int msk = 1; msk <= 32; msk <<= 1) p += __shfl_xor(p, msk);
    if (lane == 0) bfused[gi] = p + bconv[l * 512 + o];
  }
}

// =========================================================================
// Attention over batch axis. Block (512 thr) per node n; cooperative
// coalesced load of q,k,v into LDS floats (stride 1540); wave = head.
// =========================================================================
__global__ __launch_bounds__(512) void attn_kernel(
    const ushort_t* __restrict__ qkv, ushort_t* __restrict__ outp)
{
  __shared__ float qs[8 * 1540];
  __shared__ float aw[8][64];
  const int tid = threadIdx.x;
  const int n = blockIdx.x;

  const ushort_t* src = qkv + (long)n * 1536;
#pragma unroll
  for (int p = 0; p < 3; ++p) {
    int c = tid + p * 512;
    int i = c / 192, off = (c % 192) * 8;
    ushortx8 u = *(const ushortx8*)(src + (long)i * 1024 * 1536 + off);
    float* d = &qs[i * 1540 + off];
#pragma unroll
    for (int r = 0; r < 8; ++r) d[r] = b2f(u[r]);
  }
  __syncthreads();

  const int h    = tid >> 6;
  const int lane = tid & 63;
  const int i = lane >> 3, j = lane & 7;
  float s = 0.f;
#pragma unroll 8
  for (int d = 0; d < 64; ++d)
    s += qs[i * 1540 + h * 64 + d] * qs[j * 1540 + 512 + h * 64 + d];
  s *= 0.125f;

  float m = s;
  m = fmaxf(m, __shfl_xor(m, 1));
  m = fmaxf(m, __shfl_xor(m, 2));
  m = fmaxf(m, __shfl_xor(m, 4));
  float e = __expf(s - m);
  float sum = e;
  sum += __shfl_xor(sum, 1);
  sum += __shfl_xor(sum, 2);
  sum += __shfl_xor(sum, 4);
  aw[h][lane] = e / sum;

  const long ob = (long)n * 512 + h * 64 + lane;
#pragma unroll
  for (int ii = 0; ii < 8; ++ii) {
    float acc = 0.f;
#pragma unroll
    for (int jj = 0; jj < 8; ++jj)
      acc += aw[h][ii * 8 + jj] * qs[jj * 1540 + 1024 + h * 64 + lane];
    outp[ob + (long)ii * 1024 * 512] = f2b(acc);
  }
}

// =========================================================================
// x_out(bf16) = LayerNorm(x + aggA+aggB+aggC+aggD). Wave per row (512).
// =========================================================================
__global__ __launch_bounds__(256) void ln_kernel(
    const ushort_t* __restrict__ xb,
    const ushort_t* __restrict__ aggA, const ushort_t* __restrict__ aggB,
    const ushort_t* __restrict__ aggC, const ushort_t* __restrict__ aggD,
    ushort_t* __restrict__ outB)
{
  const int w = threadIdx.x >> 6, lane = threadIdx.x & 63;
  const long base = ((long)blockIdx.x * 4 + w) * 512;
  float v[8];
  float s = 0.f;
#pragma unroll
  for (int k = 0; k < 8; ++k) {
    long idx = base + lane + 64 * k;
    v[k] = b2f(xb[idx]) + b2f(aggA[idx]) + b2f(aggB[idx]) +
           b2f(aggC[idx]) + b2f(aggD[idx]);
    s += v[k];
  }
#pragma unroll
  for (int msk = 1; msk <= 32; msk <<= 1) s += __shfl_xor(s, msk);
  float mean = s * (1.f / 512.f);
  float vv = 0.f;
#pragma unroll
  for (int k = 0; k < 8; ++k) { float d = v[k] - mean; vv += d * d; }
#pragma unroll
  for (int msk = 1; msk <= 32; msk <<= 1) vv += __shfl_xor(vv, msk);
  float inv = rsqrtf(vv * (1.f / 512.f) + 1e-5f);
#pragma unroll
  for (int k = 0; k < 8; ++k)
    outB[base + lane + 64 * k] = f2b((v[k] - mean) * inv);
}

// =========================================================================
// Final layer: LN -> out_x (fp32) + fused heads (mastery, diff, h1, h2).
// =========================================================================
__global__ __launch_bounds__(256) void final_ln_heads_kernel(
    const ushort_t* __restrict__ xb,
    const ushort_t* __restrict__ aggA, const ushort_t* __restrict__ aggB,
    const ushort_t* __restrict__ aggC, const ushort_t* __restrict__ aggD,
    float* __restrict__ out_x,
    const float* __restrict__ Wcls, const float* __restrict__ bcls,
    const float* __restrict__ Wdiff, const float* __restrict__ bdiff,
    const float* __restrict__ Wpre,
    float* __restrict__ mastery, float* __restrict__ diff,
    float* __restrict__ h1, float* __restrict__ h2)
{
  const int w = threadIdx.x >> 6, lane = threadIdx.x & 63;
  const long row = (long)blockIdx.x * 4 + w;
  const long base = row * 512;
  float v[8];
  float s = 0.f;
#pragma unroll
  for (int k = 0; k < 8; ++k) {
    long idx = base + lane + 64 * k;
    v[k] = b2f(xb[idx]) + b2f(aggA[idx]) + b2f(aggB[idx]) +
           b2f(aggC[idx]) + b2f(aggD[idx]);
    s += v[k];
  }
#pragma unroll
  for (int msk = 1; msk <= 32; msk <<= 1) s += __shfl_xor(s, msk);
  float mean = s * (1.f / 512.f);
  float vv = 0.f;
#pragma unroll
  for (int k = 0; k < 8; ++k) { float d = v[k] - mean; vv += d * d; }
#pragma unroll
  for (int msk = 1; msk <= 32; msk <<= 1) vv += __shfl_xor(vv, msk);
  float inv = rsqrtf(vv * (1.f / 512.f) + 1e-5f);
#pragma unroll
  for (int k = 0; k < 8; ++k) {
    v[k] = (v[k] - mean) * inv;
    out_x[base + lane + 64 * k] = v[k];
  }
#pragma unroll
  for (int o = 0; o < 8; ++o) {
    const float* wp = (o == 0) ? Wcls
                    : (o <= 5) ? (Wdiff + (o - 1) * 512)
                    : (o == 6) ? Wpre : (Wpre + 512);
    float p = 0.f;
#pragma unroll
    for (int k = 0; k < 8; ++k) p += v[k] * wp[lane + 64 * k];
#pragma unroll
    for (int msk = 1; msk <= 32; msk <<= 1) p += __shfl_xor(p, msk);
    if (lane == 0) {
      if (o == 0)      mastery[row] = p + bcls[0];
      else if (o <= 5) diff[row * 5 + (o - 1)] = p + bdiff[o - 1];
      else if (o == 6) h1[row] = p;
      else             h2[row] = p;
    }
  }
}

// =========================================================================
// epilogue fused: [0,8192) prereq rows, [8192,8448) pool partials.
// =========================================================================
__global__ __launch_bounds__(256) void epi_kernel(
    const float* __restrict__ h1, const float* __restrict__ h2,
    const float* __restrict__ bpre, float* __restrict__ outp,
    const float* __restrict__ x, float* __restrict__ xm)
{
  const int bid = blockIdx.x;
  if (bid < 8192) {
    const int b = bid >> 10, i = bid & 1023;
    const float base = h1[b * 1024 + i] + bpre[0];
    const long ob = (long)b * (1024 * 1023) + (long)i * 1023;
#pragma unroll
    for (int r = 0; r < 4; ++r) {
      int j = r * 256 + threadIdx.x;
      if (j == i) continue;
      int pos = (j < i) ? j : j - 1;
      outp[ob + pos] = base + h2[b * 1024 + j];
    }
  } else {
    const int pb = bid - 8192;
    const int b = pb >> 5, cc = (pb >> 4) & 1, ns = pb & 15;
    const int c = cc * 256 + threadIdx.x;
    float s = 0.f;
    for (int n = ns * 64; n < ns * 64 + 64; ++n)
      s += x[((long)b * 1024 + n) * 512 + c];
    atomicAdd(&xm[b * 512 + c], s);
  }
}

// graph[b,o] = (xm[b]/1024) . Wpool[o] + b_pool[o]
__global__ __launch_bounds__(256) void graph_kernel(
    const float* __restrict__ xm, const float* __restrict__ Wpool,
    const float* __restrict__ bpool, float* __restrict__ g)
{
  const int gi = blockIdx.x * 256 + threadIdx.x;
  const int b = gi >> 9, o = gi & 511;
  float s = 0.f;
  for (int hh = 0; hh < 512; ++hh) s += xm[b * 512 + hh] * Wpool[o * 512 + hh];
  g[gi] = s * (1.f / 1024.f) + bpool[o];
}

// =========================================================================
extern "C" void kernel_launch(void* const* d_in, const int* in_sizes, int n_in,
                              void* d_out, int out_size, void* d_ws, size_t ws_size,
                              hipStream_t stream)
{
  const float* CF    = (const float*)d_in[0];
  const float* ADJ   = (const float*)d_in[1];
  const float* Wemb  = (const float*)d_in[4];
  const float* bemb  = (const float*)d_in[5];
  const float* Win   = (const float*)d_in[6];
  const float* bin   = (const float*)d_in[7];
  const float* Wout  = (const float*)d_in[8];
  const float* bout  = (const float*)d_in[9];
  const float* Wconv = (const float*)d_in[10];
  const float* bconv = (const float*)d_in[11];
  const float* Wcls  = (const float*)d_in[12];
  const float* bcls  = (const float*)d_in[13];
  const float* Wdiff = (const float*)d_in[14];
  const float* bdiff = (const float*)d_in[15];
  const float* Wpre  = (const float*)d_in[16];
  const float* bpre  = (const float*)d_in[17];
  const float* Wpool = (const float*)d_in[18];
  const float* bpool = (const float*)d_in[19];

  // ---- workspace layout (ushort units). Total ~57 MB (< proven 84 MB). ----
  ushort_t* W = (ushort_t*)d_ws;
  ushort_t* xb   = W;                       // 4194304
  ushort_t* qkvb = W + 4194304;             // 12582912 (end 16777216)
  // aliases inside the qkv region (dead when their user runs):
  ushort_t* cT    = qkvb;                   // 4194304 (conv out, post-attn)
  ushort_t* aggA  = qkvb + 4194304;         // 4194304 (split-K part 0)
  ushort_t* aggB  = qkvb + 8388608;         // 4194304 (split-K part 1)
  // precompute scratch overlays aggA region (dead after setup GEMMs):
  ushort_t* WoT   = qkvb + 4194304;         // 786432
  ushort_t* Wembb = qkvb + 4980736;         // 131072
  ushort_t* Wcb   = qkvb + 5111808;         // 786432 (end 5898240 < 8388608)
  // persistent:
  ushort_t* Winb = W + 16777216;            // 2359296
  ushort_t* Wfb  = W + 19136512;            // 786432 (fused Wconv@Wout)
  ushort_t* ADJb = W + 19922944;            // 8388608 (end 28311552)
  float* bfused = (float*)(W + 28311552);   // 1536
  float* h1     = bfused + 1536;            // 8192
  float* h2     = h1 + 8192;                // 8192
  float* xm     = h2 + 8192;                // 4096

  // ---- output layout (fp32 concat) + d_out-as-scratch aliases ----
  float* out_x       = (float*)d_out;       // 4194304
  float* out_mastery = out_x + 4194304;     // 8192
  float* out_diff    = out_mastery + 8192;  // 40960
  float* out_prereq  = out_diff + 40960;    // 8380416
  float* out_graph   = out_prereq + 8380416;// 4096
  // attn-out bf16 scratch in out_x region (dead before final LN writes it):
  ushort_t* aob = (ushort_t*)out_x;         // 4194304 ushorts
  // split-K parts 2,3 live in out_prereq region (written only by epi at end):
  ushort_t* aggC = (ushort_t*)out_prereq;            // 4194304
  ushort_t* aggD = (ushort_t*)out_prereq + 4194304;  // 4194304 (16.8M<33.5M ok)

  dim3 blk(256);

  // ---- precompute: one dispatch ----
  prep_kernel<<<dim3(6288), blk, 0, stream>>>(
      Win, Winb, Wemb, Wembb, Wconv, Wcb, ADJ, ADJb, xm,
      Wout, WoT, bout, bconv, bfused);
  // Wfused[l] = Wconv[l] @ Wout[l]  (batched z=3, 512x512x512)
  gemm_bt<1, true, 1><<<dim3(4, 4, 3), blk, 0, stream>>>(
      Wcb, WoT, nullptr, Wfb, nullptr, nullptr, nullptr,
      512, 512, 512, 262144, 262144, 262144);

  // x0 = CF @ Wemb^T + bemb  (8192 x 512 x 256, A fp32)
  gemm_bt<1, false, 1><<<dim3(4, 64, 1), blk, 0, stream>>>(
      CF, Wembb, bemb, xb, nullptr, nullptr, nullptr, 8192, 512, 256, 0, 0, 0);

  for (int l = 0; l < 3; ++l) {
    // qkv = x @ Win[l]^T + bin[l]   (8192 x 1536 x 512)
    gemm_bt<1, true, 1><<<dim3(12, 64, 1), blk, 0, stream>>>(
        xb, Winb + (long)l * 786432, bin + l * 1536,
        qkvb, nullptr, nullptr, nullptr, 8192, 1536, 512, 0, 0, 0);
    // attention over batch axis -> aob (out_x scratch)
    attn_kernel<<<dim3(1024), dim3(512), 0, stream>>>(qkvb, aob);
    // convT = (ao @ Wfused[l]^T + bfused[l]) transposed (qkv region dead)
    gemm_bt<2, true, 1><<<dim3(4, 64, 1), blk, 0, stream>>>(
        aob, Wfb + (long)l * 262144, bfused + l * 512,
        cT, nullptr, nullptr, nullptr, 8192, 512, 512, 0, 0, 0);
    // agg[b] = adj[b] @ conv[b]  (batched 1024x512x1024, split-K=4, bf16)
    gemm_bt<1, true, 4><<<dim3(4, 8, 32), blk, 0, stream>>>(
        ADJb, cT, nullptr, aggA, aggB, aggC, aggD,
        1024, 512, 1024, 1048576, 524288, 524288);
    // x = LN(x + aggA + aggB + aggC + aggD)
    if (l < 2)
      ln_kernel<<<dim3(2048), blk, 0, stream>>>(xb, aggA, aggB, aggC, aggD, xb);
    else
      final_ln_heads_kernel<<<dim3(2048), blk, 0, stream>>>(
          xb, aggA, aggB, aggC, aggD, out_x, Wcls, bcls, Wdiff, bdiff, Wpre,
          out_mastery, out_diff, h1, h2);
  }

  epi_kernel<<<dim3(8448), blk, 0, stream>>>(h1, h2, bpre, out_prereq,
                                             out_x, xm);
  graph_kernel<<<dim3(16), blk, 0, stream>>>(xm, Wpool, bpool, out_graph);
}